// Round 7
// baseline (151.094 us; speedup 1.0000x reference)
//
#include <hip/hip_runtime.h>

// SymmetricContraction as ONE bf16 MFMA GEMM:
//   t[bc, k] = sum_m P[bc, m] * Uemb[m, k] over 992 embedded rows:
//     m   0..815 : triples a<=b<=c   P = xa*xb*xc, cols 0..22  = U3sym
//     m 816..951 : pairs  a<=b       P = xa*xb,    cols 23..26 = U2sym
//     m 952..967 : singles w         P = xw,       col  27     = U1
//     m 968..991 : zero pad
// Precision identical to PASSING rounds 4/6 (absmax 2.0, threshold 16.64):
// U split hi+lo bf16 (2 MFMAs ~ fp32 U), P single RNE bf16 via
// v_cvt_pk_bf16_f32, fp32 MFMA accumulate.
//
// Round-6 post-mortem: 56us = LDS 19.5 + VALU 17 + MFMA 13 nearly SERIAL.
// Serializer: per-chunk chain P->ds_write->wait->ds_read->MFMA, with WAR on
// the single sP buffer blocking any cross-chunk overlap. Round-7 fixes:
//  (1) double-buffered sP (CH&1, compile-time): iteration = {read A(CH) from
//      buf written last iter; compute+write P(CH+1) to other buf; MFMA(CH)}
//      -> P-VALU overlaps A-read latency + MFMA, no WAR.
//  (2) MFMA order hi-pass then lo-pass: no back-to-back same-acc pairs.
//  (3) sT overlays sP: LDS 40960B -> exactly 4 blocks/CU; bounds (256,4).

#define B_   1024
#define C_   256
#define L_   16
#define E_   10
#define K3_  23
#define K2_  4

#define NM3  816
#define NM2  136
#define MTOT 992
#define NCH  31     // 992/32 chunks of K=32
#define SPSTR 20    // sP row stride in u32 (80B: 16B-aligned)
#define SPBUF (256 * SPSTR)   // one P buffer (5120 u32 = 20480 B)
#define STSTR 260   // sT row stride in floats

using f32x4   = __attribute__((ext_vector_type(4))) float;
using short8v = __attribute__((ext_vector_type(8))) short;

__device__ __host__ __forceinline__ constexpr int tri_(int n) { return n * (n + 1) / 2; }
__device__ __host__ __forceinline__ constexpr int tet_(int n) { return n * (n + 1) * (n + 2) / 6; }

// ---- compile-time multiset table: P(m) = XX[a]*XX[b]*XX[c], XX[16]=1, XX[17]=0
struct MTab { unsigned char a[MTOT], b[MTOT], c[MTOT]; };
constexpr MTab mkMT() {
  MTab t = {};
  int m = 0;
  for (int a = 0; a < 16; a++)
    for (int b = a; b < 16; b++)
      for (int c = b; c < 16; c++) { t.a[m] = a; t.b[m] = b; t.c[m] = c; ++m; }
  for (int a = 0; a < 16; a++)
    for (int b = a; b < 16; b++) { t.a[m] = a; t.b[m] = b; t.c[m] = 16; ++m; }
  for (int a = 0; a < 16; a++) { t.a[m] = a; t.b[m] = 16; t.c[m] = 16; ++m; }
  while (m < MTOT) { t.a[m] = 17; t.b[m] = 17; t.c[m] = 17; ++m; }
  return t;
}
constexpr MTab MT = mkMT();

// ---------------- prep: U rows -> hi/lo bf16 B-fragments (verbatim R6) ----
__global__ void prep_kernel(const float* __restrict__ U3, const float* __restrict__ U2,
                            const float* __restrict__ U1, unsigned short* __restrict__ wsFrag) {
  __shared__ float sRow[32][33];
  const int ch = blockIdx.x;
  const int tid = threadIdx.x;
  if (tid < 32) {
    const int m = ch * 32 + tid;
    for (int i = 0; i < 32; i++) sRow[tid][i] = 0.f;
    if (m < NM3) {
      int ia = 0;
      while (tet_(16) - tet_(16 - (ia + 1)) <= m) ia++;
      int rem = m - (tet_(16) - tet_(16 - ia));
      int ib = ia;
      while (tri_(16 - ia) - tri_(16 - (ib + 1)) <= rem) ib++;
      int ic = ib + (rem - (tri_(16 - ia) - tri_(16 - ib)));
      int pw[6] = {ia, ia, ib, ib, ic, ic};
      int pv[6] = {ib, ic, ia, ic, ia, ib};
      int pi[6] = {ic, ib, ic, ia, ib, ia};
      bool use[6];
      for (int p = 0; p < 6; p++) {
        bool dup = false;
        for (int q = 0; q < p; q++)
          dup = dup || (pw[p] == pw[q] && pv[p] == pv[q] && pi[p] == pi[q]);
        use[p] = !dup;
      }
      for (int k = 0; k < K3_; k++) {
        float s = 0.f;
        for (int p = 0; p < 6; p++)
          if (use[p]) s += U3[((pw[p] * L_ + pv[p]) * L_ + pi[p]) * K3_ + k];
        sRow[tid][k] = s;
      }
    } else if (m < NM3 + NM2) {
      const int pidx = m - NM3;
      int ia = 0;
      while (136 - tri_(16 - (ia + 1)) <= pidx) ia++;
      int ib = ia + (pidx - (136 - tri_(16 - ia)));
      for (int k2 = 0; k2 < K2_; k2++) {
        float s = U2[(ia * L_ + ib) * K2_ + k2];
        if (ia != ib) s += U2[(ib * L_ + ia) * K2_ + k2];
        sRow[tid][23 + k2] = s;
      }
    } else if (m < NM3 + NM2 + L_) {
      sRow[tid][27] = U1[m - NM3 - NM2];
    }
  }
  __syncthreads();
  if (tid < 128) {
    const int lane = tid & 63, kt = (tid >> 6) & 1;
    unsigned short hi[8], lo[8];
    for (int j = 0; j < 8; j++) {
      float v = sRow[(lane >> 4) * 8 + j][kt * 16 + (lane & 15)];
      unsigned vb = __float_as_uint(v);
      unsigned short h = (unsigned short)(vb >> 16);        // RTZ bf16 hi
      float l = v - __uint_as_float(((unsigned)h) << 16);   // exact residual
      hi[j] = h;
      lo[j] = (unsigned short)(__float_as_uint(l) >> 16);
    }
    unsigned* dst0 = (unsigned*)(wsFrag + ((size_t)((ch * 2 + kt) * 2 + 0) * 64 + lane) * 8);
    unsigned* dst1 = (unsigned*)(wsFrag + ((size_t)((ch * 2 + kt) * 2 + 1) * 64 + lane) * 8);
    for (int p = 0; p < 4; p++) {
      dst0[p] = (unsigned)hi[2 * p] | ((unsigned)hi[2 * p + 1] << 16);
      dst1[p] = (unsigned)lo[2 * p] | ((unsigned)lo[2 * p + 1] << 16);
    }
  }
}

// ---------------- main k-loop, CH as template param, dbuf pipeline ----------
#define BIDX(ch, kt, part) ((((ch) * 2 + (kt)) * 2 + (part)) * 64 + lane)

// P for chunk CH -> buffer (CH&1). All MT indices compile-time (rule #20).
// sP intentionally NOT __restrict__ (round-5 NaN lesson).
template <int CH>
__device__ __forceinline__ void p_store(const float (&XX)[18], unsigned* sP, int tid) {
  unsigned* pr = sP + (CH & 1) * SPBUF + tid * SPSTR;
  #pragma unroll
  for (int g = 0; g < 4; ++g) {
    unsigned pk[4];
    #pragma unroll
    for (int q = 0; q < 4; ++q) {
      const int m0 = CH * 32 + 2 * (g * 4 + q);
      float p0 = XX[MT.a[m0]] * XX[MT.b[m0]] * XX[MT.c[m0]];
      float p1 = XX[MT.a[m0 + 1]] * XX[MT.b[m0 + 1]] * XX[MT.c[m0 + 1]];
      asm("v_cvt_pk_bf16_f32 %0, %1, %2" : "=v"(pk[q]) : "v"(p0), "v"(p1));
    }
    *(uint4*)(pr + 4 * g) = make_uint4(pk[0], pk[1], pk[2], pk[3]);
  }
}

template <int CH>
__device__ __forceinline__ void chunk_body(
    const float (&XX)[18], unsigned* sP, const unsigned* aptrBase,
    const float4* __restrict__ Bg, int lane, int tid,
    float4 (&nb)[4], f32x4 (&acc)[4][2]) {
  // ---- A frags for CH from buf (CH&1), written LAST iteration ----
  const unsigned* ap = aptrBase + (CH & 1) * SPBUF;
  short8v A[4];
  #pragma unroll
  for (int rt = 0; rt < 4; ++rt)
    __builtin_memcpy(&A[rt], ap + rt * 16 * SPSTR, 16);

  // consume prefetched B; issue next chunk's B loads (L2-resident)
  float4 b00 = nb[0], b01 = nb[1], b10 = nb[2], b11 = nb[3];
  if constexpr (CH + 1 < NCH) {
    nb[0] = Bg[BIDX(CH + 1, 0, 0)];
    nb[1] = Bg[BIDX(CH + 1, 0, 1)];
    nb[2] = Bg[BIDX(CH + 1, 1, 0)];
    nb[3] = Bg[BIDX(CH + 1, 1, 1)];
    // ---- P for CH+1 into the OTHER buffer: overlaps A-read latency + MFMA
    p_store<CH + 1>(XX, sP, tid);
  }
  short8v B00, B01, B10, B11;
  __builtin_memcpy(&B00, &b00, 16); __builtin_memcpy(&B01, &b01, 16);
  __builtin_memcpy(&B10, &b10, 16); __builtin_memcpy(&B11, &b11, 16);

  // ---- 16 MFMAs: hi pass then lo pass (no back-to-back same-acc) ----
  #pragma unroll
  for (int rt = 0; rt < 4; ++rt)
    acc[rt][0] = __builtin_amdgcn_mfma_f32_16x16x32_bf16(A[rt], B00, acc[rt][0], 0, 0, 0);
  #pragma unroll
  for (int rt = 0; rt < 4; ++rt)
    acc[rt][1] = __builtin_amdgcn_mfma_f32_16x16x32_bf16(A[rt], B10, acc[rt][1], 0, 0, 0);
  #pragma unroll
  for (int rt = 0; rt < 4; ++rt)
    acc[rt][0] = __builtin_amdgcn_mfma_f32_16x16x32_bf16(A[rt], B01, acc[rt][0], 0, 0, 0);
  #pragma unroll
  for (int rt = 0; rt < 4; ++rt)
    acc[rt][1] = __builtin_amdgcn_mfma_f32_16x16x32_bf16(A[rt], B11, acc[rt][1], 0, 0, 0);
}

template <int CH>
struct Loop {
  static __device__ __forceinline__ void run(
      const float (&XX)[18], unsigned* sP, const unsigned* aptrBase,
      const float4* __restrict__ Bg, int lane, int tid,
      float4 (&nb)[4], f32x4 (&acc)[4][2]) {
    chunk_body<CH>(XX, sP, aptrBase, Bg, lane, tid, nb, acc);
    Loop<CH + 1>::run(XX, sP, aptrBase, Bg, lane, tid, nb, acc);
  }
};
template <>
struct Loop<NCH> {
  static __device__ __forceinline__ void run(
      const float (&)[18], unsigned*, const unsigned*,
      const float4* __restrict__, int, int, float4 (&)[4], f32x4 (&)[4][2]) {}
};

// grid = 1024 blocks (one per b), 256 threads = 4 waves; wave w owns sP rows
// [w*64, w*64+64) in both buffers -> zero barriers in the k-loop.
__global__ __launch_bounds__(256, 4) void symcon_kernel(
    const float* __restrict__ x,   // [B,C,L]
    const float* __restrict__ y,   // [B,E]
    const float* __restrict__ W3,  // [E,K3,C]
    const float* __restrict__ W2,  // [E,K2,C]
    const float* __restrict__ W1,  // [E,1,C]
    const unsigned short* __restrict__ wsFrag,
    float* __restrict__ out)       // [B,C]
{
  __shared__ unsigned smemU[2 * SPBUF];       // 40960 B; sP dbuf, reused as sT
  unsigned* sP = smemU;
  float* sT = (float*)smemU;                  // [28][STSTR] = 29120 B fits

  const int tid = threadIdx.x, c = tid, b = blockIdx.x;
  const int lane = tid & 63;

  // x row -> 18 registers (constant indices only)
  float XX[18];
  {
    const float4* xg = (const float4*)(x + ((size_t)b * C_ + c) * L_);
    #pragma unroll
    for (int i = 0; i < 4; i++) {
      float4 v = xg[i];
      XX[i * 4 + 0] = v.x; XX[i * 4 + 1] = v.y;
      XX[i * 4 + 2] = v.z; XX[i * 4 + 3] = v.w;
    }
    XX[16] = 1.f; XX[17] = 0.f;
  }

  const float4* Bg = (const float4*)wsFrag;
  float4 nb[4];
  nb[0] = Bg[BIDX(0, 0, 0)]; nb[1] = Bg[BIDX(0, 0, 1)];
  nb[2] = Bg[BIDX(0, 1, 0)]; nb[3] = Bg[BIDX(0, 1, 1)];

  f32x4 acc[4][2];
  #pragma unroll
  for (int rt = 0; rt < 4; rt++)
    #pragma unroll
    for (int kt = 0; kt < 2; kt++) acc[rt][kt] = (f32x4)0.f;

  const unsigned* aptrBase =
      sP + ((tid & 192) + (tid & 15)) * SPSTR + ((tid >> 4) & 3) * 4;

  // prologue: P(0) -> buf0 (same wave, in-order DS: no barrier needed)
  p_store<0>(XX, sP, tid);
  Loop<0>::run(XX, sP, aptrBase, Bg, lane, tid, nb, acc);

  // ---- transpose t to thread-c layout via sT (sT overlays sP: barrier) ----
  __syncthreads();
  const int wrow = tid & 192;
  #pragma unroll
  for (int rt = 0; rt < 4; ++rt) {
    const int c0 = wrow + rt * 16 + ((tid >> 4) & 3) * 4;  // D rows (bc)
    {
      const int k = tid & 15;                               // kt=0 cols 0..15
      *(f32x4*)&sT[k * STSTR + c0] = acc[rt][0];
    }
    if ((tid & 15) < 12) {                                  // kt=1 cols 16..27
      const int k = 16 + (tid & 15);
      *(f32x4*)&sT[k * STSTR + c0] = acc[rt][1];
    }
  }
  // own-wave column band readback: no second barrier needed (verified R6)
  float t[28];
  #pragma unroll
  for (int k = 0; k < 28; ++k) t[k] = sT[k * STSTR + tid];

  // ---- epilogue (verbatim from verified rounds) ----
  float yreg[E_];
  #pragma unroll
  for (int e = 0; e < E_; e++) yreg[e] = y[b * E_ + e];

  float result = 0.f;
  #pragma unroll
  for (int k = 0; k < K3_; k++) {
    const float* w3p = &W3[k * C_ + c];
    float w3k = 0.f;
    #pragma unroll
    for (int e = 0; e < E_; e++) w3k += w3p[e * K3_ * C_] * yreg[e];
    result += t[k] * w3k;
  }
  #pragma unroll
  for (int k2 = 0; k2 < K2_; k2++) {
    const float* w2p = &W2[k2 * C_ + c];
    float w2k = 0.f;
    #pragma unroll
    for (int e = 0; e < E_; e++) w2k += w2p[e * K2_ * C_] * yreg[e];
    result += t[23 + k2] * w2k;
  }
  {
    float w1v = 0.f;
    #pragma unroll
    for (int e = 0; e < E_; e++) w1v += W1[e * C_ + c] * yreg[e];
    result += t[27] * w1v;
  }

  out[(size_t)b * C_ + c] = result;
}

extern "C" void kernel_launch(void* const* d_in, const int* in_sizes, int n_in,
                              void* d_out, int out_size, void* d_ws, size_t ws_size,
                              hipStream_t stream) {
  const float* x  = (const float*)d_in[0];
  const float* y  = (const float*)d_in[1];
  const float* U3 = (const float*)d_in[2];
  const float* U2 = (const float*)d_in[3];
  const float* U1 = (const float*)d_in[4];
  const float* W3 = (const float*)d_in[5];
  const float* W2 = (const float*)d_in[6];
  const float* W1 = (const float*)d_in[7];
  float* out = (float*)d_out;

  unsigned short* wsFrag = (unsigned short*)d_ws;  // NCH*2*2*64*8 u16 = 126976 B

  prep_kernel<<<dim3(NCH), dim3(256), 0, stream>>>(U3, U2, U1, wsFrag);
  symcon_kernel<<<dim3(B_), dim3(256), 0, stream>>>(
      x, y, W3, W2, W1, wsFrag, out);
}

// Round 8
// 148.584 us; speedup vs baseline: 1.0169x; 1.0169x over previous
//
#include <hip/hip_runtime.h>

// SymmetricContraction as ONE bf16 MFMA GEMM:
//   t[bc, k] = sum_m P[bc, m] * Uemb[m, k] over 992 embedded rows:
//     m   0..815 : triples a<=b<=c   P = xa*xb*xc, cols 0..22  = U3sym
//     m 816..951 : pairs  a<=b       P = xa*xb,    cols 23..26 = U2sym
//     m 952..967 : singles w         P = xw,       col  27     = U1
//     m 968..991 : zero pad
// Precision identical to PASSING rounds 4/6/7 (absmax 2.0, threshold 16.64):
// U split hi+lo bf16 (2 MFMAs ~ fp32 U), P single RNE bf16 via
// v_cvt_pk_bf16_f32, fp32 MFMA accumulate.
//
// Round-7 post-mortem: __launch_bounds__(256,4) capped VGPR at 512/4=128 but
// the dbuf pipeline's live set is ~130 -> spill cascade (VGPR_Count 64,
// WRITE_SIZE 6.4->77MB scratch traffic, dur 68us). The pipeline never got a
// fair test. Round-8: identical code, bounds back to (256,3) (cap ~168, like
// R6's no-spill build). 3 blocks/CU (VGPR-shaped), LDS 40960*3=120KB fits.

#define B_   1024
#define C_   256
#define L_   16
#define E_   10
#define K3_  23
#define K2_  4

#define NM3  816
#define NM2  136
#define MTOT 992
#define NCH  31     // 992/32 chunks of K=32
#define SPSTR 20    // sP row stride in u32 (80B: 16B-aligned)
#define SPBUF (256 * SPSTR)   // one P buffer (5120 u32 = 20480 B)
#define STSTR 260   // sT row stride in floats

using f32x4   = __attribute__((ext_vector_type(4))) float;
using short8v = __attribute__((ext_vector_type(8))) short;

__device__ __host__ __forceinline__ constexpr int tri_(int n) { return n * (n + 1) / 2; }
__device__ __host__ __forceinline__ constexpr int tet_(int n) { return n * (n + 1) * (n + 2) / 6; }

// ---- compile-time multiset table: P(m) = XX[a]*XX[b]*XX[c], XX[16]=1, XX[17]=0
struct MTab { unsigned char a[MTOT], b[MTOT], c[MTOT]; };
constexpr MTab mkMT() {
  MTab t = {};
  int m = 0;
  for (int a = 0; a < 16; a++)
    for (int b = a; b < 16; b++)
      for (int c = b; c < 16; c++) { t.a[m] = a; t.b[m] = b; t.c[m] = c; ++m; }
  for (int a = 0; a < 16; a++)
    for (int b = a; b < 16; b++) { t.a[m] = a; t.b[m] = b; t.c[m] = 16; ++m; }
  for (int a = 0; a < 16; a++) { t.a[m] = a; t.b[m] = 16; t.c[m] = 16; ++m; }
  while (m < MTOT) { t.a[m] = 17; t.b[m] = 17; t.c[m] = 17; ++m; }
  return t;
}
constexpr MTab MT = mkMT();

// ---------------- prep: U rows -> hi/lo bf16 B-fragments (verbatim R6) ----
__global__ void prep_kernel(const float* __restrict__ U3, const float* __restrict__ U2,
                            const float* __restrict__ U1, unsigned short* __restrict__ wsFrag) {
  __shared__ float sRow[32][33];
  const int ch = blockIdx.x;
  const int tid = threadIdx.x;
  if (tid < 32) {
    const int m = ch * 32 + tid;
    for (int i = 0; i < 32; i++) sRow[tid][i] = 0.f;
    if (m < NM3) {
      int ia = 0;
      while (tet_(16) - tet_(16 - (ia + 1)) <= m) ia++;
      int rem = m - (tet_(16) - tet_(16 - ia));
      int ib = ia;
      while (tri_(16 - ia) - tri_(16 - (ib + 1)) <= rem) ib++;
      int ic = ib + (rem - (tri_(16 - ia) - tri_(16 - ib)));
      int pw[6] = {ia, ia, ib, ib, ic, ic};
      int pv[6] = {ib, ic, ia, ic, ia, ib};
      int pi[6] = {ic, ib, ic, ia, ib, ia};
      bool use[6];
      for (int p = 0; p < 6; p++) {
        bool dup = false;
        for (int q = 0; q < p; q++)
          dup = dup || (pw[p] == pw[q] && pv[p] == pv[q] && pi[p] == pi[q]);
        use[p] = !dup;
      }
      for (int k = 0; k < K3_; k++) {
        float s = 0.f;
        for (int p = 0; p < 6; p++)
          if (use[p]) s += U3[((pw[p] * L_ + pv[p]) * L_ + pi[p]) * K3_ + k];
        sRow[tid][k] = s;
      }
    } else if (m < NM3 + NM2) {
      const int pidx = m - NM3;
      int ia = 0;
      while (136 - tri_(16 - (ia + 1)) <= pidx) ia++;
      int ib = ia + (pidx - (136 - tri_(16 - ia)));
      for (int k2 = 0; k2 < K2_; k2++) {
        float s = U2[(ia * L_ + ib) * K2_ + k2];
        if (ia != ib) s += U2[(ib * L_ + ia) * K2_ + k2];
        sRow[tid][23 + k2] = s;
      }
    } else if (m < NM3 + NM2 + L_) {
      sRow[tid][27] = U1[m - NM3 - NM2];
    }
  }
  __syncthreads();
  if (tid < 128) {
    const int lane = tid & 63, kt = (tid >> 6) & 1;
    unsigned short hi[8], lo[8];
    for (int j = 0; j < 8; j++) {
      float v = sRow[(lane >> 4) * 8 + j][kt * 16 + (lane & 15)];
      unsigned vb = __float_as_uint(v);
      unsigned short h = (unsigned short)(vb >> 16);        // RTZ bf16 hi
      float l = v - __uint_as_float(((unsigned)h) << 16);   // exact residual
      hi[j] = h;
      lo[j] = (unsigned short)(__float_as_uint(l) >> 16);
    }
    unsigned* dst0 = (unsigned*)(wsFrag + ((size_t)((ch * 2 + kt) * 2 + 0) * 64 + lane) * 8);
    unsigned* dst1 = (unsigned*)(wsFrag + ((size_t)((ch * 2 + kt) * 2 + 1) * 64 + lane) * 8);
    for (int p = 0; p < 4; p++) {
      dst0[p] = (unsigned)hi[2 * p] | ((unsigned)hi[2 * p + 1] << 16);
      dst1[p] = (unsigned)lo[2 * p] | ((unsigned)lo[2 * p + 1] << 16);
    }
  }
}

// ---------------- main k-loop, CH as template param, dbuf pipeline ----------
#define BIDX(ch, kt, part) ((((ch) * 2 + (kt)) * 2 + (part)) * 64 + lane)

// P for chunk CH -> buffer (CH&1). All MT indices compile-time (rule #20).
// sP intentionally NOT __restrict__ (round-5 NaN lesson).
template <int CH>
__device__ __forceinline__ void p_store(const float (&XX)[18], unsigned* sP, int tid) {
  unsigned* pr = sP + (CH & 1) * SPBUF + tid * SPSTR;
  #pragma unroll
  for (int g = 0; g < 4; ++g) {
    unsigned pk[4];
    #pragma unroll
    for (int q = 0; q < 4; ++q) {
      const int m0 = CH * 32 + 2 * (g * 4 + q);
      float p0 = XX[MT.a[m0]] * XX[MT.b[m0]] * XX[MT.c[m0]];
      float p1 = XX[MT.a[m0 + 1]] * XX[MT.b[m0 + 1]] * XX[MT.c[m0 + 1]];
      asm("v_cvt_pk_bf16_f32 %0, %1, %2" : "=v"(pk[q]) : "v"(p0), "v"(p1));
    }
    *(uint4*)(pr + 4 * g) = make_uint4(pk[0], pk[1], pk[2], pk[3]);
  }
}

template <int CH>
__device__ __forceinline__ void chunk_body(
    const float (&XX)[18], unsigned* sP, const unsigned* aptrBase,
    const float4* __restrict__ Bg, int lane, int tid,
    float4 (&nb)[4], f32x4 (&acc)[4][2]) {
  // ---- A frags for CH from buf (CH&1), written LAST iteration ----
  const unsigned* ap = aptrBase + (CH & 1) * SPBUF;
  short8v A[4];
  #pragma unroll
  for (int rt = 0; rt < 4; ++rt)
    __builtin_memcpy(&A[rt], ap + rt * 16 * SPSTR, 16);

  // consume prefetched B; issue next chunk's B loads (L2-resident)
  float4 b00 = nb[0], b01 = nb[1], b10 = nb[2], b11 = nb[3];
  if constexpr (CH + 1 < NCH) {
    nb[0] = Bg[BIDX(CH + 1, 0, 0)];
    nb[1] = Bg[BIDX(CH + 1, 0, 1)];
    nb[2] = Bg[BIDX(CH + 1, 1, 0)];
    nb[3] = Bg[BIDX(CH + 1, 1, 1)];
    // ---- P for CH+1 into the OTHER buffer: overlaps A-read latency + MFMA
    p_store<CH + 1>(XX, sP, tid);
  }
  short8v B00, B01, B10, B11;
  __builtin_memcpy(&B00, &b00, 16); __builtin_memcpy(&B01, &b01, 16);
  __builtin_memcpy(&B10, &b10, 16); __builtin_memcpy(&B11, &b11, 16);

  // ---- 16 MFMAs: hi pass then lo pass (no back-to-back same-acc) ----
  #pragma unroll
  for (int rt = 0; rt < 4; ++rt)
    acc[rt][0] = __builtin_amdgcn_mfma_f32_16x16x32_bf16(A[rt], B00, acc[rt][0], 0, 0, 0);
  #pragma unroll
  for (int rt = 0; rt < 4; ++rt)
    acc[rt][1] = __builtin_amdgcn_mfma_f32_16x16x32_bf16(A[rt], B10, acc[rt][1], 0, 0, 0);
  #pragma unroll
  for (int rt = 0; rt < 4; ++rt)
    acc[rt][0] = __builtin_amdgcn_mfma_f32_16x16x32_bf16(A[rt], B01, acc[rt][0], 0, 0, 0);
  #pragma unroll
  for (int rt = 0; rt < 4; ++rt)
    acc[rt][1] = __builtin_amdgcn_mfma_f32_16x16x32_bf16(A[rt], B11, acc[rt][1], 0, 0, 0);
}

template <int CH>
struct Loop {
  static __device__ __forceinline__ void run(
      const float (&XX)[18], unsigned* sP, const unsigned* aptrBase,
      const float4* __restrict__ Bg, int lane, int tid,
      float4 (&nb)[4], f32x4 (&acc)[4][2]) {
    chunk_body<CH>(XX, sP, aptrBase, Bg, lane, tid, nb, acc);
    Loop<CH + 1>::run(XX, sP, aptrBase, Bg, lane, tid, nb, acc);
  }
};
template <>
struct Loop<NCH> {
  static __device__ __forceinline__ void run(
      const float (&)[18], unsigned*, const unsigned*,
      const float4* __restrict__, int, int, float4 (&)[4], f32x4 (&)[4][2]) {}
};

// grid = 1024 blocks (one per b), 256 threads = 4 waves; wave w owns sP rows
// [w*64, w*64+64) in both buffers -> zero barriers in the k-loop.
// bounds (256,3): VGPR cap ~168 -- the dbuf live set (~130) FITS. (256,4)'s
// 128-cap caused the round-7 spill cascade.
__global__ __launch_bounds__(256, 3) void symcon_kernel(
    const float* __restrict__ x,   // [B,C,L]
    const float* __restrict__ y,   // [B,E]
    const float* __restrict__ W3,  // [E,K3,C]
    const float* __restrict__ W2,  // [E,K2,C]
    const float* __restrict__ W1,  // [E,1,C]
    const unsigned short* __restrict__ wsFrag,
    float* __restrict__ out)       // [B,C]
{
  __shared__ unsigned smemU[2 * SPBUF];       // 40960 B; sP dbuf, reused as sT
  unsigned* sP = smemU;
  float* sT = (float*)smemU;                  // [28][STSTR] = 29120 B fits

  const int tid = threadIdx.x, c = tid, b = blockIdx.x;
  const int lane = tid & 63;

  // x row -> 18 registers (constant indices only)
  float XX[18];
  {
    const float4* xg = (const float4*)(x + ((size_t)b * C_ + c) * L_);
    #pragma unroll
    for (int i = 0; i < 4; i++) {
      float4 v = xg[i];
      XX[i * 4 + 0] = v.x; XX[i * 4 + 1] = v.y;
      XX[i * 4 + 2] = v.z; XX[i * 4 + 3] = v.w;
    }
    XX[16] = 1.f; XX[17] = 0.f;
  }

  const float4* Bg = (const float4*)wsFrag;
  float4 nb[4];
  nb[0] = Bg[BIDX(0, 0, 0)]; nb[1] = Bg[BIDX(0, 0, 1)];
  nb[2] = Bg[BIDX(0, 1, 0)]; nb[3] = Bg[BIDX(0, 1, 1)];

  f32x4 acc[4][2];
  #pragma unroll
  for (int rt = 0; rt < 4; rt++)
    #pragma unroll
    for (int kt = 0; kt < 2; kt++) acc[rt][kt] = (f32x4)0.f;

  const unsigned* aptrBase =
      sP + ((tid & 192) + (tid & 15)) * SPSTR + ((tid >> 4) & 3) * 4;

  // prologue: P(0) -> buf0 (same wave, in-order DS: no barrier needed)
  p_store<0>(XX, sP, tid);
  Loop<0>::run(XX, sP, aptrBase, Bg, lane, tid, nb, acc);

  // ---- transpose t to thread-c layout via sT (sT overlays sP: barrier) ----
  __syncthreads();
  const int wrow = tid & 192;
  #pragma unroll
  for (int rt = 0; rt < 4; ++rt) {
    const int c0 = wrow + rt * 16 + ((tid >> 4) & 3) * 4;  // D rows (bc)
    {
      const int k = tid & 15;                               // kt=0 cols 0..15
      *(f32x4*)&sT[k * STSTR + c0] = acc[rt][0];
    }
    if ((tid & 15) < 12) {                                  // kt=1 cols 16..27
      const int k = 16 + (tid & 15);
      *(f32x4*)&sT[k * STSTR + c0] = acc[rt][1];
    }
  }
  // own-wave column band readback: no second barrier needed (verified R6)
  float t[28];
  #pragma unroll
  for (int k = 0; k < 28; ++k) t[k] = sT[k * STSTR + tid];

  // ---- epilogue (verbatim from verified rounds) ----
  float yreg[E_];
  #pragma unroll
  for (int e = 0; e < E_; e++) yreg[e] = y[b * E_ + e];

  float result = 0.f;
  #pragma unroll
  for (int k = 0; k < K3_; k++) {
    const float* w3p = &W3[k * C_ + c];
    float w3k = 0.f;
    #pragma unroll
    for (int e = 0; e < E_; e++) w3k += w3p[e * K3_ * C_] * yreg[e];
    result += t[k] * w3k;
  }
  #pragma unroll
  for (int k2 = 0; k2 < K2_; k2++) {
    const float* w2p = &W2[k2 * C_ + c];
    float w2k = 0.f;
    #pragma unroll
    for (int e = 0; e < E_; e++) w2k += w2p[e * K2_ * C_] * yreg[e];
    result += t[23 + k2] * w2k;
  }
  {
    float w1v = 0.f;
    #pragma unroll
    for (int e = 0; e < E_; e++) w1v += W1[e * C_ + c] * yreg[e];
    result += t[27] * w1v;
  }

  out[(size_t)b * C_ + c] = result;
}

extern "C" void kernel_launch(void* const* d_in, const int* in_sizes, int n_in,
                              void* d_out, int out_size, void* d_ws, size_t ws_size,
                              hipStream_t stream) {
  const float* x  = (const float*)d_in[0];
  const float* y  = (const float*)d_in[1];
  const float* U3 = (const float*)d_in[2];
  const float* U2 = (const float*)d_in[3];
  const float* U1 = (const float*)d_in[4];
  const float* W3 = (const float*)d_in[5];
  const float* W2 = (const float*)d_in[6];
  const float* W1 = (const float*)d_in[7];
  float* out = (float*)d_out;

  unsigned short* wsFrag = (unsigned short*)d_ws;  // NCH*2*2*64*8 u16 = 126976 B

  prep_kernel<<<dim3(NCH), dim3(256), 0, stream>>>(U3, U2, U1, wsFrag);
  symcon_kernel<<<dim3(B_), dim3(256), 0, stream>>>(
      x, y, W3, W2, W1, wsFrag, out);
}

// Round 9
// 145.871 us; speedup vs baseline: 1.0358x; 1.0186x over previous
//
#include <hip/hip_runtime.h>

// SymmetricContraction as ONE bf16 MFMA GEMM:
//   t[bc, k] = sum_m P[bc, m] * Uemb[m, k] over 992 embedded rows:
//     m   0..815 : triples a<=b<=c   P = xa*xb*xc, cols 0..22  = U3sym
//     m 816..951 : pairs  a<=b       P = xa*xb,    cols 23..26 = U2sym
//     m 952..967 : singles w         P = xw,       col  27     = U1
//     m 968..991 : zero pad
// Precision identical to PASSING rounds 4/6/7/8 (absmax 2.0, threshold 16.64):
// U split hi+lo bf16 (2 MFMAs ~ fp32 U), P single RNE bf16 via
// v_cvt_pk_bf16_f32, fp32 MFMA accumulate.
//
// Round-8 post-mortem: explicit dbuf pipeline LOST to the R6 structure
// (68 vs 56us; Common-mistake #5 — compiler already schedules fine). R6's
// residual gap is EXPOSED LATENCY: occupancy 23.6% because grid 1024 at
// (256,3) = 768 blocks 3-resident + 256-block STRAGGLER phase at 1/CU.
// Round-9: exact R6 kernel, only __launch_bounds__(256,4): grid 1024 =
// 256 CUs x 4 blocks -> single phase, 16 waves/CU, 4 waves/SIMD TLP.
// VGPR 84 <= 128 cap (no R7 spill), LDS 29184*4 = 117KB <= 160KB.
// Bank-conflict counter understood & benign: b128 x 64 lanes is inherently
// 8 bank-passes; measured excess ~2 cyc/read. Not a target.

#define B_   1024
#define C_   256
#define L_   16
#define E_   10
#define K3_  23
#define K2_  4

#define NM3  816
#define NM2  136
#define MTOT 992
#define NCH  31     // 992/32 chunks of K=32
#define SPSTR 20    // sP row stride in u32 (80B: 16B-aligned, 8-residue spread)
#define STSTR 260   // sT row stride in floats

using f32x4   = __attribute__((ext_vector_type(4))) float;
using short8v = __attribute__((ext_vector_type(8))) short;

__device__ __host__ __forceinline__ constexpr int tri_(int n) { return n * (n + 1) / 2; }
__device__ __host__ __forceinline__ constexpr int tet_(int n) { return n * (n + 1) * (n + 2) / 6; }

// ---- compile-time multiset table: P(m) = XX[a]*XX[b]*XX[c], XX[16]=1, XX[17]=0
struct MTab { unsigned char a[MTOT], b[MTOT], c[MTOT]; };
constexpr MTab mkMT() {
  MTab t = {};
  int m = 0;
  for (int a = 0; a < 16; a++)
    for (int b = a; b < 16; b++)
      for (int c = b; c < 16; c++) { t.a[m] = a; t.b[m] = b; t.c[m] = c; ++m; }
  for (int a = 0; a < 16; a++)
    for (int b = a; b < 16; b++) { t.a[m] = a; t.b[m] = b; t.c[m] = 16; ++m; }
  for (int a = 0; a < 16; a++) { t.a[m] = a; t.b[m] = 16; t.c[m] = 16; ++m; }
  while (m < MTOT) { t.a[m] = 17; t.b[m] = 17; t.c[m] = 17; ++m; }
  return t;
}
constexpr MTab MT = mkMT();

// ---------------- prep: U rows -> hi/lo bf16 B-fragments (verbatim R6) ----
__global__ void prep_kernel(const float* __restrict__ U3, const float* __restrict__ U2,
                            const float* __restrict__ U1, unsigned short* __restrict__ wsFrag) {
  __shared__ float sRow[32][33];
  const int ch = blockIdx.x;
  const int tid = threadIdx.x;
  if (tid < 32) {
    const int m = ch * 32 + tid;
    for (int i = 0; i < 32; i++) sRow[tid][i] = 0.f;
    if (m < NM3) {
      int ia = 0;
      while (tet_(16) - tet_(16 - (ia + 1)) <= m) ia++;
      int rem = m - (tet_(16) - tet_(16 - ia));
      int ib = ia;
      while (tri_(16 - ia) - tri_(16 - (ib + 1)) <= rem) ib++;
      int ic = ib + (rem - (tri_(16 - ia) - tri_(16 - ib)));
      int pw[6] = {ia, ia, ib, ib, ic, ic};
      int pv[6] = {ib, ic, ia, ic, ia, ib};
      int pi[6] = {ic, ib, ic, ia, ib, ia};
      bool use[6];
      for (int p = 0; p < 6; p++) {
        bool dup = false;
        for (int q = 0; q < p; q++)
          dup = dup || (pw[p] == pw[q] && pv[p] == pv[q] && pi[p] == pi[q]);
        use[p] = !dup;
      }
      for (int k = 0; k < K3_; k++) {
        float s = 0.f;
        for (int p = 0; p < 6; p++)
          if (use[p]) s += U3[((pw[p] * L_ + pv[p]) * L_ + pi[p]) * K3_ + k];
        sRow[tid][k] = s;
      }
    } else if (m < NM3 + NM2) {
      const int pidx = m - NM3;
      int ia = 0;
      while (136 - tri_(16 - (ia + 1)) <= pidx) ia++;
      int ib = ia + (pidx - (136 - tri_(16 - ia)));
      for (int k2 = 0; k2 < K2_; k2++) {
        float s = U2[(ia * L_ + ib) * K2_ + k2];
        if (ia != ib) s += U2[(ib * L_ + ia) * K2_ + k2];
        sRow[tid][23 + k2] = s;
      }
    } else if (m < NM3 + NM2 + L_) {
      sRow[tid][27] = U1[m - NM3 - NM2];
    }
  }
  __syncthreads();
  if (tid < 128) {
    const int lane = tid & 63, kt = (tid >> 6) & 1;
    unsigned short hi[8], lo[8];
    for (int j = 0; j < 8; j++) {
      float v = sRow[(lane >> 4) * 8 + j][kt * 16 + (lane & 15)];
      unsigned vb = __float_as_uint(v);
      unsigned short h = (unsigned short)(vb >> 16);        // RTZ bf16 hi
      float l = v - __uint_as_float(((unsigned)h) << 16);   // exact residual
      hi[j] = h;
      lo[j] = (unsigned short)(__float_as_uint(l) >> 16);
    }
    unsigned* dst0 = (unsigned*)(wsFrag + ((size_t)((ch * 2 + kt) * 2 + 0) * 64 + lane) * 8);
    unsigned* dst1 = (unsigned*)(wsFrag + ((size_t)((ch * 2 + kt) * 2 + 1) * 64 + lane) * 8);
    for (int p = 0; p < 4; p++) {
      dst0[p] = (unsigned)hi[2 * p] | ((unsigned)hi[2 * p + 1] << 16);
      dst1[p] = (unsigned)lo[2 * p] | ((unsigned)lo[2 * p + 1] << 16);
    }
  }
}

// ---------------- main k-loop body, CH as TEMPLATE param (verbatim R6) ----
#define BIDX(ch, kt, part) ((((ch) * 2 + (kt)) * 2 + (part)) * 64 + lane)

// NOTE: sP pointers intentionally NOT __restrict__ — P-store and A-read alias
// inside sP (the round-5 NaN). Compiler must keep ds_write -> ds_read order.
template <int CH>
__device__ __forceinline__ void chunk_body(
    const float (&XX)[18], unsigned* pr, const unsigned* aptr,
    const float4* __restrict__ Bg, int lane, float4 (&nb)[4], f32x4 (&acc)[4][2]) {
  // ---- P for this thread's row: 32 values -> 16 packed bf16 pairs ----
  // All MT indices are compile-time constants => XX[] stays in VGPRs.
  #pragma unroll
  for (int g = 0; g < 4; ++g) {
    unsigned pk[4];
    #pragma unroll
    for (int q = 0; q < 4; ++q) {
      const int m0 = CH * 32 + 2 * (g * 4 + q);
      float p0 = XX[MT.a[m0]] * XX[MT.b[m0]] * XX[MT.c[m0]];
      float p1 = XX[MT.a[m0 + 1]] * XX[MT.b[m0 + 1]] * XX[MT.c[m0 + 1]];
      asm("v_cvt_pk_bf16_f32 %0, %1, %2" : "=v"(pk[q]) : "v"(p0), "v"(p1));
    }
    *(uint4*)(pr + 4 * g) = make_uint4(pk[0], pk[1], pk[2], pk[3]);
  }

  // consume prefetched B frags; issue next chunk's loads (L2-resident)
  float4 b00 = nb[0], b01 = nb[1], b10 = nb[2], b11 = nb[3];
  if constexpr (CH + 1 < NCH) {
    nb[0] = Bg[BIDX(CH + 1, 0, 0)];
    nb[1] = Bg[BIDX(CH + 1, 0, 1)];
    nb[2] = Bg[BIDX(CH + 1, 1, 0)];
    nb[3] = Bg[BIDX(CH + 1, 1, 1)];
  }
  short8v B00, B01, B10, B11;
  __builtin_memcpy(&B00, &b00, 16); __builtin_memcpy(&B01, &b01, 16);
  __builtin_memcpy(&B10, &b10, 16); __builtin_memcpy(&B11, &b11, 16);

  // ---- A frags from own wave's sP rows (compile-time rt offsets); 16 MFMAs
  #pragma unroll
  for (int rt = 0; rt < 4; ++rt) {
    short8v A;
    __builtin_memcpy(&A, aptr + rt * 16 * SPSTR, 16);
    acc[rt][0] = __builtin_amdgcn_mfma_f32_16x16x32_bf16(A, B00, acc[rt][0], 0, 0, 0);
    acc[rt][0] = __builtin_amdgcn_mfma_f32_16x16x32_bf16(A, B01, acc[rt][0], 0, 0, 0);
    acc[rt][1] = __builtin_amdgcn_mfma_f32_16x16x32_bf16(A, B10, acc[rt][1], 0, 0, 0);
    acc[rt][1] = __builtin_amdgcn_mfma_f32_16x16x32_bf16(A, B11, acc[rt][1], 0, 0, 0);
  }
}

template <int CH>
struct Loop {
  static __device__ __forceinline__ void run(
      const float (&XX)[18], unsigned* pr, const unsigned* aptr,
      const float4* __restrict__ Bg, int lane, float4 (&nb)[4], f32x4 (&acc)[4][2]) {
    chunk_body<CH>(XX, pr, aptr, Bg, lane, nb, acc);
    Loop<CH + 1>::run(XX, pr, aptr, Bg, lane, nb, acc);
  }
};
template <>
struct Loop<NCH> {
  static __device__ __forceinline__ void run(
      const float (&)[18], unsigned*, const unsigned*,
      const float4* __restrict__, int, float4 (&)[4], f32x4 (&)[4][2]) {}
};

// grid = 1024 blocks (one per b), 256 threads = 4 waves; wave w owns sP rows
// [w*64, w*64+64) -> zero barriers in the k-loop.
// (256,4): 4 blocks/CU, single dispatch phase (1024 = 256x4), 4 waves/SIMD.
// R6's 84 VGPR fits the 128 cap (R7's spill was the dbuf live set, not this).
__global__ __launch_bounds__(256, 4) void symcon_kernel(
    const float* __restrict__ x,   // [B,C,L]
    const float* __restrict__ y,   // [B,E]
    const float* __restrict__ W3,  // [E,K3,C]
    const float* __restrict__ W2,  // [E,K2,C]
    const float* __restrict__ W1,  // [E,1,C]
    const unsigned short* __restrict__ wsFrag,
    float* __restrict__ out)       // [B,C]
{
  __shared__ float smem[28 * STSTR];          // 29120 B; sP (20KB) reused as sT
  unsigned* sP = (unsigned*)smem;             // [256][SPSTR] u32 (bf16 pairs)
  float* sT = smem;                           // [28][STSTR]

  const int tid = threadIdx.x, c = tid, b = blockIdx.x;
  const int lane = tid & 63;

  // x row -> 18 registers (constant indices only)
  float XX[18];
  {
    const float4* xg = (const float4*)(x + ((size_t)b * C_ + c) * L_);
    #pragma unroll
    for (int i = 0; i < 4; i++) {
      float4 v = xg[i];
      XX[i * 4 + 0] = v.x; XX[i * 4 + 1] = v.y;
      XX[i * 4 + 2] = v.z; XX[i * 4 + 3] = v.w;
    }
    XX[16] = 1.f; XX[17] = 0.f;
  }

  const float4* Bg = (const float4*)wsFrag;
  float4 nb[4];
  nb[0] = Bg[BIDX(0, 0, 0)]; nb[1] = Bg[BIDX(0, 0, 1)];
  nb[2] = Bg[BIDX(0, 1, 0)]; nb[3] = Bg[BIDX(0, 1, 1)];

  f32x4 acc[4][2];
  #pragma unroll
  for (int rt = 0; rt < 4; rt++)
    #pragma unroll
    for (int kt = 0; kt < 2; kt++) acc[rt][kt] = (f32x4)0.f;

  unsigned* pr = sP + tid * SPSTR;
  const unsigned* aptr = sP + ((tid & 192) + (tid & 15)) * SPSTR + ((tid >> 4) & 3) * 4;

  Loop<0>::run(XX, pr, aptr, Bg, lane, nb, acc);

  // ---- transpose t to thread-c layout via sT (one barrier; own-wave cols) ----
  __syncthreads();
  const int wrow = tid & 192;
  #pragma unroll
  for (int rt = 0; rt < 4; ++rt) {
    const int c0 = wrow + rt * 16 + ((tid >> 4) & 3) * 4;  // D rows (bc)
    {
      const int k = tid & 15;                               // kt=0 cols 0..15
      *(f32x4*)&sT[k * STSTR + c0] = acc[rt][0];
    }
    if ((tid & 15) < 12) {                                  // kt=1 cols 16..27
      const int k = 16 + (tid & 15);
      *(f32x4*)&sT[k * STSTR + c0] = acc[rt][1];
    }
  }
  float t[28];
  #pragma unroll
  for (int k = 0; k < 28; ++k) t[k] = sT[k * STSTR + tid];

  // ---- epilogue (verbatim from verified rounds) ----
  float yreg[E_];
  #pragma unroll
  for (int e = 0; e < E_; e++) yreg[e] = y[b * E_ + e];

  float result = 0.f;
  #pragma unroll
  for (int k = 0; k < K3_; k++) {
    const float* w3p = &W3[k * C_ + c];
    float w3k = 0.f;
    #pragma unroll
    for (int e = 0; e < E_; e++) w3k += w3p[e * K3_ * C_] * yreg[e];
    result += t[k] * w3k;
  }
  #pragma unroll
  for (int k2 = 0; k2 < K2_; k2++) {
    const float* w2p = &W2[k2 * C_ + c];
    float w2k = 0.f;
    #pragma unroll
    for (int e = 0; e < E_; e++) w2k += w2p[e * K2_ * C_] * yreg[e];
    result += t[23 + k2] * w2k;
  }
  {
    float w1v = 0.f;
    #pragma unroll
    for (int e = 0; e < E_; e++) w1v += W1[e * C_ + c] * yreg[e];
    result += t[27] * w1v;
  }

  out[(size_t)b * C_ + c] = result;
}

extern "C" void kernel_launch(void* const* d_in, const int* in_sizes, int n_in,
                              void* d_out, int out_size, void* d_ws, size_t ws_size,
                              hipStream_t stream) {
  const float* x  = (const float*)d_in[0];
  const float* y  = (const float*)d_in[1];
  const float* U3 = (const float*)d_in[2];
  const float* U2 = (const float*)d_in[3];
  const float* U1 = (const float*)d_in[4];
  const float* W3 = (const float*)d_in[5];
  const float* W2 = (const float*)d_in[6];
  const float* W1 = (const float*)d_in[7];
  float* out = (float*)d_out;

  unsigned short* wsFrag = (unsigned short*)d_ws;  // NCH*2*2*64*8 u16 = 126976 B

  prep_kernel<<<dim3(NCH), dim3(256), 0, stream>>>(U3, U2, U1, wsFrag);
  symcon_kernel<<<dim3(B_), dim3(256), 0, stream>>>(
      x, y, W3, W2, W1, wsFrag, out);
}

// Round 10
// 144.099 us; speedup vs baseline: 1.0485x; 1.0123x over previous
//
#include <hip/hip_runtime.h>

// SymmetricContraction as ONE bf16 MFMA GEMM:
//   t[bc, k] = sum_m P[bc, m] * Uemb[m, k] over 992 embedded rows:
//     m   0..815 : triples a<=b<=c   P = xa*xb*xc, cols 0..22  = U3sym
//     m 816..951 : pairs  a<=b       P = xa*xb,    cols 23..26 = U2sym
//     m 952..967 : singles w         P = xw,       col  27     = U1
//     m 968..991 : zero pad
// Precision identical to PASSING rounds 4/6-9 (absmax 2.0, threshold 16.64):
// U split hi+lo bf16 (2 MFMAs ~ fp32 U), P single RNE bf16 via
// v_cvt_pk_bf16_f32, fp32 MFMA accumulate.
//
// Round-9 post-mortem: launch_bounds(256,N) is treated as a MINIMUM waves/EU;
// hipcc opportunistically targets 2N (arg3 -> 84=512/6 regs, arg4 -> 64=512/8)
// and at arg=4 spills ~26 regs -> 125MB scratch round-trip = the limiter.
// Round-10: pin occupancy with amdgpu_waves_per_eu(4,4) (min=max=4): true
// 128-reg budget, R6's 84-reg live set fits -> clean 4 blocks/CU, single
// dispatch phase (1024 = 256x4), no straggler drain. Kernel body = verified R6.

#define B_   1024
#define C_   256
#define L_   16
#define E_   10
#define K3_  23
#define K2_  4

#define NM3  816
#define NM2  136
#define MTOT 992
#define NCH  31     // 992/32 chunks of K=32
#define SPSTR 20    // sP row stride in u32 (80B: 16B-aligned, 8-residue spread)
#define STSTR 260   // sT row stride in floats

using f32x4   = __attribute__((ext_vector_type(4))) float;
using short8v = __attribute__((ext_vector_type(8))) short;

__device__ __host__ __forceinline__ constexpr int tri_(int n) { return n * (n + 1) / 2; }
__device__ __host__ __forceinline__ constexpr int tet_(int n) { return n * (n + 1) * (n + 2) / 6; }

// ---- compile-time multiset table: P(m) = XX[a]*XX[b]*XX[c], XX[16]=1, XX[17]=0
struct MTab { unsigned char a[MTOT], b[MTOT], c[MTOT]; };
constexpr MTab mkMT() {
  MTab t = {};
  int m = 0;
  for (int a = 0; a < 16; a++)
    for (int b = a; b < 16; b++)
      for (int c = b; c < 16; c++) { t.a[m] = a; t.b[m] = b; t.c[m] = c; ++m; }
  for (int a = 0; a < 16; a++)
    for (int b = a; b < 16; b++) { t.a[m] = a; t.b[m] = b; t.c[m] = 16; ++m; }
  for (int a = 0; a < 16; a++) { t.a[m] = a; t.b[m] = 16; t.c[m] = 16; ++m; }
  while (m < MTOT) { t.a[m] = 17; t.b[m] = 17; t.c[m] = 17; ++m; }
  return t;
}
constexpr MTab MT = mkMT();

// ---------------- prep: U rows -> hi/lo bf16 B-fragments (verbatim R6) ----
__global__ void prep_kernel(const float* __restrict__ U3, const float* __restrict__ U2,
                            const float* __restrict__ U1, unsigned short* __restrict__ wsFrag) {
  __shared__ float sRow[32][33];
  const int ch = blockIdx.x;
  const int tid = threadIdx.x;
  if (tid < 32) {
    const int m = ch * 32 + tid;
    for (int i = 0; i < 32; i++) sRow[tid][i] = 0.f;
    if (m < NM3) {
      int ia = 0;
      while (tet_(16) - tet_(16 - (ia + 1)) <= m) ia++;
      int rem = m - (tet_(16) - tet_(16 - ia));
      int ib = ia;
      while (tri_(16 - ia) - tri_(16 - (ib + 1)) <= rem) ib++;
      int ic = ib + (rem - (tri_(16 - ia) - tri_(16 - ib)));
      int pw[6] = {ia, ia, ib, ib, ic, ic};
      int pv[6] = {ib, ic, ia, ic, ia, ib};
      int pi[6] = {ic, ib, ic, ia, ib, ia};
      bool use[6];
      for (int p = 0; p < 6; p++) {
        bool dup = false;
        for (int q = 0; q < p; q++)
          dup = dup || (pw[p] == pw[q] && pv[p] == pv[q] && pi[p] == pi[q]);
        use[p] = !dup;
      }
      for (int k = 0; k < K3_; k++) {
        float s = 0.f;
        for (int p = 0; p < 6; p++)
          if (use[p]) s += U3[((pw[p] * L_ + pv[p]) * L_ + pi[p]) * K3_ + k];
        sRow[tid][k] = s;
      }
    } else if (m < NM3 + NM2) {
      const int pidx = m - NM3;
      int ia = 0;
      while (136 - tri_(16 - (ia + 1)) <= pidx) ia++;
      int ib = ia + (pidx - (136 - tri_(16 - ia)));
      for (int k2 = 0; k2 < K2_; k2++) {
        float s = U2[(ia * L_ + ib) * K2_ + k2];
        if (ia != ib) s += U2[(ib * L_ + ia) * K2_ + k2];
        sRow[tid][23 + k2] = s;
      }
    } else if (m < NM3 + NM2 + L_) {
      sRow[tid][27] = U1[m - NM3 - NM2];
    }
  }
  __syncthreads();
  if (tid < 128) {
    const int lane = tid & 63, kt = (tid >> 6) & 1;
    unsigned short hi[8], lo[8];
    for (int j = 0; j < 8; j++) {
      float v = sRow[(lane >> 4) * 8 + j][kt * 16 + (lane & 15)];
      unsigned vb = __float_as_uint(v);
      unsigned short h = (unsigned short)(vb >> 16);        // RTZ bf16 hi
      float l = v - __uint_as_float(((unsigned)h) << 16);   // exact residual
      hi[j] = h;
      lo[j] = (unsigned short)(__float_as_uint(l) >> 16);
    }
    unsigned* dst0 = (unsigned*)(wsFrag + ((size_t)((ch * 2 + kt) * 2 + 0) * 64 + lane) * 8);
    unsigned* dst1 = (unsigned*)(wsFrag + ((size_t)((ch * 2 + kt) * 2 + 1) * 64 + lane) * 8);
    for (int p = 0; p < 4; p++) {
      dst0[p] = (unsigned)hi[2 * p] | ((unsigned)hi[2 * p + 1] << 16);
      dst1[p] = (unsigned)lo[2 * p] | ((unsigned)lo[2 * p + 1] << 16);
    }
  }
}

// ---------------- main k-loop body, CH as TEMPLATE param (verbatim R6) ----
#define BIDX(ch, kt, part) ((((ch) * 2 + (kt)) * 2 + (part)) * 64 + lane)

// NOTE: sP pointers intentionally NOT __restrict__ — P-store and A-read alias
// inside sP (the round-5 NaN). Compiler must keep ds_write -> ds_read order.
template <int CH>
__device__ __forceinline__ void chunk_body(
    const float (&XX)[18], unsigned* pr, const unsigned* aptr,
    const float4* __restrict__ Bg, int lane, float4 (&nb)[4], f32x4 (&acc)[4][2]) {
  // ---- P for this thread's row: 32 values -> 16 packed bf16 pairs ----
  // All MT indices are compile-time constants => XX[] stays in VGPRs.
  #pragma unroll
  for (int g = 0; g < 4; ++g) {
    unsigned pk[4];
    #pragma unroll
    for (int q = 0; q < 4; ++q) {
      const int m0 = CH * 32 + 2 * (g * 4 + q);
      float p0 = XX[MT.a[m0]] * XX[MT.b[m0]] * XX[MT.c[m0]];
      float p1 = XX[MT.a[m0 + 1]] * XX[MT.b[m0 + 1]] * XX[MT.c[m0 + 1]];
      asm("v_cvt_pk_bf16_f32 %0, %1, %2" : "=v"(pk[q]) : "v"(p0), "v"(p1));
    }
    *(uint4*)(pr + 4 * g) = make_uint4(pk[0], pk[1], pk[2], pk[3]);
  }

  // consume prefetched B frags; issue next chunk's loads (L2-resident)
  float4 b00 = nb[0], b01 = nb[1], b10 = nb[2], b11 = nb[3];
  if constexpr (CH + 1 < NCH) {
    nb[0] = Bg[BIDX(CH + 1, 0, 0)];
    nb[1] = Bg[BIDX(CH + 1, 0, 1)];
    nb[2] = Bg[BIDX(CH + 1, 1, 0)];
    nb[3] = Bg[BIDX(CH + 1, 1, 1)];
  }
  short8v B00, B01, B10, B11;
  __builtin_memcpy(&B00, &b00, 16); __builtin_memcpy(&B01, &b01, 16);
  __builtin_memcpy(&B10, &b10, 16); __builtin_memcpy(&B11, &b11, 16);

  // ---- A frags from own wave's sP rows (compile-time rt offsets); 16 MFMAs
  #pragma unroll
  for (int rt = 0; rt < 4; ++rt) {
    short8v A;
    __builtin_memcpy(&A, aptr + rt * 16 * SPSTR, 16);
    acc[rt][0] = __builtin_amdgcn_mfma_f32_16x16x32_bf16(A, B00, acc[rt][0], 0, 0, 0);
    acc[rt][0] = __builtin_amdgcn_mfma_f32_16x16x32_bf16(A, B01, acc[rt][0], 0, 0, 0);
    acc[rt][1] = __builtin_amdgcn_mfma_f32_16x16x32_bf16(A, B10, acc[rt][1], 0, 0, 0);
    acc[rt][1] = __builtin_amdgcn_mfma_f32_16x16x32_bf16(A, B11, acc[rt][1], 0, 0, 0);
  }
}

template <int CH>
struct Loop {
  static __device__ __forceinline__ void run(
      const float (&XX)[18], unsigned* pr, const unsigned* aptr,
      const float4* __restrict__ Bg, int lane, float4 (&nb)[4], f32x4 (&acc)[4][2]) {
    chunk_body<CH>(XX, pr, aptr, Bg, lane, nb, acc);
    Loop<CH + 1>::run(XX, pr, aptr, Bg, lane, nb, acc);
  }
};
template <>
struct Loop<NCH> {
  static __device__ __forceinline__ void run(
      const float (&)[18], unsigned*, const unsigned*,
      const float4* __restrict__, int, float4 (&)[4], f32x4 (&)[4][2]) {}
};

// grid = 1024 blocks (one per b), 256 threads = 4 waves; wave w owns sP rows
// [w*64, w*64+64) -> zero barriers in the k-loop.
// amdgpu_waves_per_eu(4,4): PIN occupancy at 4 waves/EU (= 4 blocks/CU for
// 256-thr blocks) -> VGPR budget is a true 128; stops hipcc's "minimum"
// interpretation from targeting 8 waves @ 64 regs and spilling (R7/R9).
__global__ __launch_bounds__(256)
__attribute__((amdgpu_waves_per_eu(4, 4)))
void symcon_kernel(
    const float* __restrict__ x,   // [B,C,L]
    const float* __restrict__ y,   // [B,E]
    const float* __restrict__ W3,  // [E,K3,C]
    const float* __restrict__ W2,  // [E,K2,C]
    const float* __restrict__ W1,  // [E,1,C]
    const unsigned short* __restrict__ wsFrag,
    float* __restrict__ out)       // [B,C]
{
  __shared__ float smem[28 * STSTR];          // 29120 B; sP (20KB) reused as sT
  unsigned* sP = (unsigned*)smem;             // [256][SPSTR] u32 (bf16 pairs)
  float* sT = smem;                           // [28][STSTR]

  const int tid = threadIdx.x, c = tid, b = blockIdx.x;
  const int lane = tid & 63;

  // x row -> 18 registers (constant indices only)
  float XX[18];
  {
    const float4* xg = (const float4*)(x + ((size_t)b * C_ + c) * L_);
    #pragma unroll
    for (int i = 0; i < 4; i++) {
      float4 v = xg[i];
      XX[i * 4 + 0] = v.x; XX[i * 4 + 1] = v.y;
      XX[i * 4 + 2] = v.z; XX[i * 4 + 3] = v.w;
    }
    XX[16] = 1.f; XX[17] = 0.f;
  }

  const float4* Bg = (const float4*)wsFrag;
  float4 nb[4];
  nb[0] = Bg[BIDX(0, 0, 0)]; nb[1] = Bg[BIDX(0, 0, 1)];
  nb[2] = Bg[BIDX(0, 1, 0)]; nb[3] = Bg[BIDX(0, 1, 1)];

  f32x4 acc[4][2];
  #pragma unroll
  for (int rt = 0; rt < 4; rt++)
    #pragma unroll
    for (int kt = 0; kt < 2; kt++) acc[rt][kt] = (f32x4)0.f;

  unsigned* pr = sP + tid * SPSTR;
  const unsigned* aptr = sP + ((tid & 192) + (tid & 15)) * SPSTR + ((tid >> 4) & 3) * 4;

  Loop<0>::run(XX, pr, aptr, Bg, lane, nb, acc);

  // ---- transpose t to thread-c layout via sT (one barrier; own-wave cols) ----
  __syncthreads();
  const int wrow = tid & 192;
  #pragma unroll
  for (int rt = 0; rt < 4; ++rt) {
    const int c0 = wrow + rt * 16 + ((tid >> 4) & 3) * 4;  // D rows (bc)
    {
      const int k = tid & 15;                               // kt=0 cols 0..15
      *(f32x4*)&sT[k * STSTR + c0] = acc[rt][0];
    }
    if ((tid & 15) < 12) {                                  // kt=1 cols 16..27
      const int k = 16 + (tid & 15);
      *(f32x4*)&sT[k * STSTR + c0] = acc[rt][1];
    }
  }
  float t[28];
  #pragma unroll
  for (int k = 0; k < 28; ++k) t[k] = sT[k * STSTR + tid];

  // ---- epilogue (verbatim from verified rounds) ----
  float yreg[E_];
  #pragma unroll
  for (int e = 0; e < E_; e++) yreg[e] = y[b * E_ + e];

  float result = 0.f;
  #pragma unroll
  for (int k = 0; k < K3_; k++) {
    const float* w3p = &W3[k * C_ + c];
    float w3k = 0.f;
    #pragma unroll
    for (int e = 0; e < E_; e++) w3k += w3p[e * K3_ * C_] * yreg[e];
    result += t[k] * w3k;
  }
  #pragma unroll
  for (int k2 = 0; k2 < K2_; k2++) {
    const float* w2p = &W2[k2 * C_ + c];
    float w2k = 0.f;
    #pragma unroll
    for (int e = 0; e < E_; e++) w2k += w2p[e * K2_ * C_] * yreg[e];
    result += t[23 + k2] * w2k;
  }
  {
    float w1v = 0.f;
    #pragma unroll
    for (int e = 0; e < E_; e++) w1v += W1[e * C_ + c] * yreg[e];
    result += t[27] * w1v;
  }

  out[(size_t)b * C_ + c] = result;
}

extern "C" void kernel_launch(void* const* d_in, const int* in_sizes, int n_in,
                              void* d_out, int out_size, void* d_ws, size_t ws_size,
                              hipStream_t stream) {
  const float* x  = (const float*)d_in[0];
  const float* y  = (const float*)d_in[1];
  const float* U3 = (const float*)d_in[2];
  const float* U2 = (const float*)d_in[3];
  const float* U1 = (const float*)d_in[4];
  const float* W3 = (const float*)d_in[5];
  const float* W2 = (const float*)d_in[6];
  const float* W1 = (const float*)d_in[7];
  float* out = (float*)d_out;

  unsigned short* wsFrag = (unsigned short*)d_ws;  // NCH*2*2*64*8 u16 = 126976 B

  prep_kernel<<<dim3(NCH), dim3(256), 0, stream>>>(U3, U2, U1, wsFrag);
  symcon_kernel<<<dim3(B_), dim3(256), 0, stream>>>(
      x, y, W3, W2, W1, wsFrag, out);
}

// Round 11
// 131.004 us; speedup vs baseline: 1.1534x; 1.1000x over previous
//
#include <hip/hip_runtime.h>

// SymmetricContraction as ONE bf16 MFMA GEMM (32x32x16 form):
//   t[ch, k] = sum_m P[ch, m] * Uemb[m, k] over 976 embedded rows (61 K=16
//   chunks; the all-pad chunk 61 is dropped):
//     m   0..815 : triples a<=b<=c   P = xa*xb*xc, cols 0..22  = U3sym
//     m 816..951 : pairs  a<=b       P = xa*xb,    cols 23..26 = U2sym
//     m 952..967 : singles w         P = xw,       col  27     = U1
//     m 968..975 : zero pad (XX[17]=0 path)
// Precision identical to PASSING rounds 4/6-10 (absmax 2.0, thr 16.64):
// U split hi+lo bf16 (2 MFMAs ~ fp32 U), P single RNE bf16, fp32 accum.
//
// WHY 32x32: with M=32 only TWO lanes (l, l+32) share an A-row, so lane l
// (owning channel wavebase+l) computes its 16 P-values per chunk directly in
// fragment order: pk0 = k-slice 0..7, pk1 = k-slice 8..15. One
// v_permlane32_swap_b32 (vdst.hi <-> vsrc.lo) per dword converts {pk0,pk1}
// in place into the A-frags of BOTH channel-group MFMAs:
//   A0 = {lo: own pk0, hi: partner's pk1}, A1 = {lo: partner's pk0, hi: own pk1}.
// => the per-chunk LDS write->read P-transpose (R6: ~20us of LDS pipe) is
// GONE, N=28 fits ONE 32-wide tile (half the MFMA issues), live set ~75 regs.
// R9/R10 lesson: allocator targets 2x the launch-bounds min (arg3->85,
// arg4->64+spill). launch_bounds(256,2) -> aims 4 waves/EU = 128-reg budget.

#define B_   1024
#define C_   256
#define L_   16
#define E_   10
#define K3_  23
#define K2_  4

#define NM3  816
#define NM2  136
#define MTOT 992
#define NCH2 61      // K=16 chunks 0..60
#define STSTR 260    // sT row stride in floats

using f32x4   = __attribute__((ext_vector_type(4))) float;
using f32x16  = __attribute__((ext_vector_type(16))) float;
using short8v = __attribute__((ext_vector_type(8))) short;

__device__ __host__ __forceinline__ constexpr int tri_(int n) { return n * (n + 1) / 2; }
__device__ __host__ __forceinline__ constexpr int tet_(int n) { return n * (n + 1) * (n + 2) / 6; }

// ---- compile-time multiset table: P(m) = XX[a]*XX[b]*XX[c], XX[16]=1, XX[17]=0
struct MTab { unsigned char a[MTOT], b[MTOT], c[MTOT]; };
constexpr MTab mkMT() {
  MTab t = {};
  int m = 0;
  for (int a = 0; a < 16; a++)
    for (int b = a; b < 16; b++)
      for (int c = b; c < 16; c++) { t.a[m] = a; t.b[m] = b; t.c[m] = c; ++m; }
  for (int a = 0; a < 16; a++)
    for (int b = a; b < 16; b++) { t.a[m] = a; t.b[m] = b; t.c[m] = 16; ++m; }
  for (int a = 0; a < 16; a++) { t.a[m] = a; t.b[m] = 16; t.c[m] = 16; ++m; }
  while (m < MTOT) { t.a[m] = 17; t.b[m] = 17; t.c[m] = 17; ++m; }
  return t;
}
constexpr MTab MT = mkMT();

// ---------------- prep: U rows -> hi/lo bf16 B-frags for 32x32x16 ----------
// grid = 61 blocks x 128 threads. Threads 0..15 build the 16 U-rows of chunk
// ch in LDS (closed-form m -> indices); all 128 pack: lane=tid&63 part=tid>>6.
// B-frag: lane l holds Uemb[m = ch*16 + (l>>5)*8 + j][col = l&31], j asc,
// dword p = (m=2p, 2p+1) as (lo,hi) -- SAME k-placement convention as the
// A-side pk packing (any HW k-permutation cancels; proven by R4/R6 passing).
__global__ void prep_kernel(const float* __restrict__ U3, const float* __restrict__ U2,
                            const float* __restrict__ U1, unsigned short* __restrict__ wsFrag) {
  __shared__ float sRow[16][36];
  const int ch = blockIdx.x;       // 0..60
  const int tid = threadIdx.x;     // 0..127
  if (tid < 16) {
    const int m = ch * 16 + tid;
    for (int i = 0; i < 36; i++) sRow[tid][i] = 0.f;
    if (m < NM3) {
      int ia = 0;
      while (tet_(16) - tet_(16 - (ia + 1)) <= m) ia++;
      int rem = m - (tet_(16) - tet_(16 - ia));
      int ib = ia;
      while (tri_(16 - ia) - tri_(16 - (ib + 1)) <= rem) ib++;
      int ic = ib + (rem - (tri_(16 - ia) - tri_(16 - ib)));
      int pw[6] = {ia, ia, ib, ib, ic, ic};
      int pv[6] = {ib, ic, ia, ic, ia, ib};
      int pi[6] = {ic, ib, ic, ia, ib, ia};
      bool use[6];
      for (int p = 0; p < 6; p++) {
        bool dup = false;
        for (int q = 0; q < p; q++)
          dup = dup || (pw[p] == pw[q] && pv[p] == pv[q] && pi[p] == pi[q]);
        use[p] = !dup;
      }
      for (int k = 0; k < K3_; k++) {
        float s = 0.f;
        for (int p = 0; p < 6; p++)
          if (use[p]) s += U3[((pw[p] * L_ + pv[p]) * L_ + pi[p]) * K3_ + k];
        sRow[tid][k] = s;
      }
    } else if (m < NM3 + NM2) {
      const int pidx = m - NM3;
      int ia = 0;
      while (136 - tri_(16 - (ia + 1)) <= pidx) ia++;
      int ib = ia + (pidx - (136 - tri_(16 - ia)));
      for (int k2 = 0; k2 < K2_; k2++) {
        float s = U2[(ia * L_ + ib) * K2_ + k2];
        if (ia != ib) s += U2[(ib * L_ + ia) * K2_ + k2];
        sRow[tid][23 + k2] = s;
      }
    } else if (m < NM3 + NM2 + L_) {
      sRow[tid][27] = U1[m - NM3 - NM2];
    }
  }
  __syncthreads();
  {
    const int lane = tid & 63, part = tid >> 6;   // part 0 = hi-bf16, 1 = lo-residual
    unsigned short v16[8];
    for (int j = 0; j < 8; j++) {
      float v = sRow[(lane >> 5) * 8 + j][lane & 31];
      unsigned vb = __float_as_uint(v);
      unsigned short h = (unsigned short)(vb >> 16);        // RTZ bf16 hi
      if (part == 0) {
        v16[j] = h;
      } else {
        float lres = v - __uint_as_float(((unsigned)h) << 16);  // exact residual
        v16[j] = (unsigned short)(__float_as_uint(lres) >> 16);
      }
    }
    unsigned* dst = (unsigned*)(wsFrag + ((size_t)(ch * 2 + part) * 64 + lane) * 8);
    for (int p = 0; p < 4; p++)
      dst[p] = (unsigned)v16[2 * p] | ((unsigned)v16[2 * p + 1] << 16);
  }
}

// ---------------- permlane32_swap: vdst.hi <-> vsrc.lo (both updated) ------
__device__ __forceinline__ void lane32_swap(unsigned& a, unsigned& b) {
#if defined(__has_builtin) && __has_builtin(__builtin_amdgcn_permlane32_swap)
  auto r = __builtin_amdgcn_permlane32_swap((int)a, (int)b, false, false);
  a = (unsigned)r[0];
  b = (unsigned)r[1];
#else
  asm volatile("v_permlane32_swap_b32 %0, %1" : "+v"(a), "+v"(b));
#endif
}

// ---------------- main k-loop body, CH as TEMPLATE param -------------------
template <int CH>
__device__ __forceinline__ void chunk_body(
    const float (&XX)[18], const float4* __restrict__ Bg, int lane,
    float4& nbH, float4& nbL, f32x16& acc0, f32x16& acc1) {
  // P for THIS lane's channel: k-slice 0 (m=CH*16+0..7) -> pk0,
  // k-slice 1 (m=CH*16+8..15) -> pk1. All MT indices compile-time (rule #20).
  unsigned pk0[4], pk1[4];
  #pragma unroll
  for (int i = 0; i < 4; ++i) {
    {
      const int m0 = CH * 16 + 2 * i;
      float p0 = XX[MT.a[m0]] * XX[MT.b[m0]] * XX[MT.c[m0]];
      float p1 = XX[MT.a[m0 + 1]] * XX[MT.b[m0 + 1]] * XX[MT.c[m0 + 1]];
      asm("v_cvt_pk_bf16_f32 %0, %1, %2" : "=v"(pk0[i]) : "v"(p0), "v"(p1));
    }
    {
      const int m0 = CH * 16 + 8 + 2 * i;
      float p0 = XX[MT.a[m0]] * XX[MT.b[m0]] * XX[MT.c[m0]];
      float p1 = XX[MT.a[m0 + 1]] * XX[MT.b[m0 + 1]] * XX[MT.c[m0 + 1]];
      asm("v_cvt_pk_bf16_f32 %0, %1, %2" : "=v"(pk1[i]) : "v"(p0), "v"(p1));
    }
    // pk0[i] -> A0[i] = {lo: own pk0, hi: partner pk1}
    // pk1[i] -> A1[i] = {lo: partner pk0, hi: own pk1}
    lane32_swap(pk0[i], pk1[i]);
  }

  // consume prefetched B (hi+lo U parts); issue next chunk's loads (L2-res.)
  float4 bh = nbH, bl = nbL;
  if constexpr (CH + 1 < NCH2) {
    nbH = Bg[(CH + 1) * 128 + lane];
    nbL = Bg[(CH + 1) * 128 + 64 + lane];
  }
  short8v A0, A1, BH, BL;
  __builtin_memcpy(&A0, pk0, 16);
  __builtin_memcpy(&A1, pk1, 16);
  __builtin_memcpy(&BH, &bh, 16);
  __builtin_memcpy(&BL, &bl, 16);

  acc0 = __builtin_amdgcn_mfma_f32_32x32x16_bf16(A0, BH, acc0, 0, 0, 0);
  acc1 = __builtin_amdgcn_mfma_f32_32x32x16_bf16(A1, BH, acc1, 0, 0, 0);
  acc0 = __builtin_amdgcn_mfma_f32_32x32x16_bf16(A0, BL, acc0, 0, 0, 0);
  acc1 = __builtin_amdgcn_mfma_f32_32x32x16_bf16(A1, BL, acc1, 0, 0, 0);
}

template <int CH>
struct Loop {
  static __device__ __forceinline__ void run(
      const float (&XX)[18], const float4* __restrict__ Bg, int lane,
      float4& nbH, float4& nbL, f32x16& acc0, f32x16& acc1) {
    chunk_body<CH>(XX, Bg, lane, nbH, nbL, acc0, acc1);
    Loop<CH + 1>::run(XX, Bg, lane, nbH, nbL, acc0, acc1);
  }
};
template <>
struct Loop<NCH2> {
  static __device__ __forceinline__ void run(
      const float (&)[18], const float4* __restrict__, int, float4&, float4&,
      f32x16&, f32x16&) {}
};

// grid = 1024 blocks (one per b), 256 threads = 4 waves. Lane l of wave w
// owns channel w*64 + l. acc0 = channels w*64+0..31, acc1 = +32. ZERO LDS in
// the main loop. launch_bounds(256,2): allocator aims 4 waves/EU (128 regs).
__global__ __launch_bounds__(256, 2) void symcon_kernel(
    const float* __restrict__ x,   // [B,C,L]
    const float* __restrict__ y,   // [B,E]
    const float* __restrict__ W3,  // [E,K3,C]
    const float* __restrict__ W2,  // [E,K2,C]
    const float* __restrict__ W1,  // [E,1,C]
    const unsigned short* __restrict__ wsFrag,
    float* __restrict__ out)       // [B,C]
{
  __shared__ __attribute__((aligned(16))) float sT[28 * STSTR];  // 29120 B

  const int tid = threadIdx.x, c = tid, b = blockIdx.x;
  const int lane = tid & 63;
  const int wid = tid >> 6;

  // x row of this thread's channel -> 18 registers (constant indices only)
  float XX[18];
  {
    const float4* xg = (const float4*)(x + ((size_t)b * C_ + c) * L_);
    #pragma unroll
    for (int i = 0; i < 4; i++) {
      float4 v = xg[i];
      XX[i * 4 + 0] = v.x; XX[i * 4 + 1] = v.y;
      XX[i * 4 + 2] = v.z; XX[i * 4 + 3] = v.w;
    }
    XX[16] = 1.f; XX[17] = 0.f;
  }

  const float4* Bg = (const float4*)wsFrag;
  float4 nbH = Bg[lane], nbL = Bg[64 + lane];
  f32x16 acc0 = (f32x16)0.f, acc1 = (f32x16)0.f;

  Loop<0>::run(XX, Bg, lane, nbH, nbL, acc0, acc1);

  // ---- D -> sT transpose. D layout (m74/m101-verified): lane l, reg r holds
  // t[ch = (r&3)+8*(r>>2)+4*(l>>5) (+32 for acc1)][kcol = l&31].
  // Each reg-quad r=4q..4q+3 = 4 consecutive channels -> b128 store.
  const int kcol = lane & 31, hi = lane >> 5;
  if (kcol < 28) {
    #pragma unroll
    for (int q = 0; q < 4; ++q) {
      f32x4 v0, v1;
      #pragma unroll
      for (int i2 = 0; i2 < 4; ++i2) {
        v0[i2] = acc0[4 * q + i2];
        v1[i2] = acc1[4 * q + i2];
      }
      *(f32x4*)&sT[kcol * STSTR + wid * 64 +      8 * q + 4 * hi] = v0;
      *(f32x4*)&sT[kcol * STSTR + wid * 64 + 32 + 8 * q + 4 * hi] = v1;
    }
  }
  __syncthreads();
  float t[28];
  #pragma unroll
  for (int k = 0; k < 28; ++k) t[k] = sT[k * STSTR + tid];

  // ---- epilogue (verbatim from verified rounds) ----
  float yreg[E_];
  #pragma unroll
  for (int e = 0; e < E_; e++) yreg[e] = y[b * E_ + e];

  float result = 0.f;
  #pragma unroll
  for (int k = 0; k < K3_; k++) {
    const float* w3p = &W3[k * C_ + c];
    float w3k = 0.f;
    #pragma unroll
    for (int e = 0; e < E_; e++) w3k += w3p[e * K3_ * C_] * yreg[e];
    result += t[k] * w3k;
  }
  #pragma unroll
  for (int k2 = 0; k2 < K2_; k2++) {
    const float* w2p = &W2[k2 * C_ + c];
    float w2k = 0.f;
    #pragma unroll
    for (int e = 0; e < E_; e++) w2k += w2p[e * K2_ * C_] * yreg[e];
    result += t[23 + k2] * w2k;
  }
  {
    float w1v = 0.f;
    #pragma unroll
    for (int e = 0; e < E_; e++) w1v += W1[e * C_ + c] * yreg[e];
    result += t[27] * w1v;
  }

  out[(size_t)b * C_ + c] = result;
}

extern "C" void kernel_launch(void* const* d_in, const int* in_sizes, int n_in,
                              void* d_out, int out_size, void* d_ws, size_t ws_size,
                              hipStream_t stream) {
  const float* x  = (const float*)d_in[0];
  const float* y  = (const float*)d_in[1];
  const float* U3 = (const float*)d_in[2];
  const float* U2 = (const float*)d_in[3];
  const float* U1 = (const float*)d_in[4];
  const float* W3 = (const float*)d_in[5];
  const float* W2 = (const float*)d_in[6];
  const float* W1 = (const float*)d_in[7];
  float* out = (float*)d_out;

  unsigned short* wsFrag = (unsigned short*)d_ws;  // 61*2*64*8 u16 = 124928 B

  prep_kernel<<<dim3(NCH2), dim3(128), 0, stream>>>(U3, U2, U1, wsFrag);
  symcon_kernel<<<dim3(B_), dim3(256), 0, stream>>>(
      x, y, W3, W2, W1, wsFrag, out);
}

// Round 12
// 129.730 us; speedup vs baseline: 1.1647x; 1.0098x over previous
//
#include <hip/hip_runtime.h>

// SymmetricContraction as ONE bf16 MFMA GEMM (32x32x16 form):
//   t[ch, k] = sum_m P[ch, m] * Uemb[m, k] over 976 embedded rows (61 K=16
//   chunks):
//     m   0..815 : triples a<=b<=c   P = xa*xb*xc, cols 0..22  = U3sym
//     m 816..951 : pairs  a<=b       P = xa*xb,    cols 23..26 = U2sym
//     m 952..967 : singles w         P = xw,       col  27     = U1
//     m 968..975 : zero pad (XX[17]=0 path)
// Precision identical to PASSING rounds 4/6-11 (absmax 2.0, thr 16.64):
// U split hi+lo bf16 (2 MFMAs ~ fp32 U), P single RNE bf16, fp32 accum.
//
// Round-11 post-mortem: structure won (bank-conflicts 0, no spills) but
// LATENCY-BOUND at Occupancy 18.9% (~1.5 waves/SIMD): MfmaUtil 25% = MFMA
// work done in 4x its saturation time; per-chunk chain mul->cvt->permlane->
// MFMA + 1-deep L2 B-load exposed. The wave is fully self-contained (even
// the D-transpose readback stays in its own sT band) -> the 256-thr block +
// barrier only COUPLED residency. Round-12:
//  (1) 1-WAVE BLOCKS: 64 thr, grid 4096 (b = bb>>2, chan-group = bb&3),
//      zero barriers, 16 blocks/CU ceiling, scheduler free.
//  (2) 2-chunk-deep B prefetch (compile-time parity, named pairs).
// Math bit-identical to R11.

#define B_   1024
#define C_   256
#define L_   16
#define E_   10
#define K3_  23
#define K2_  4

#define NM3  816
#define NM2  136
#define MTOT 992
#define NCH2 61      // K=16 chunks 0..60
#define STSTR 68     // sT row stride in floats (28 rows x 68 = 7616 B)

using f32x4   = __attribute__((ext_vector_type(4))) float;
using f32x16  = __attribute__((ext_vector_type(16))) float;
using short8v = __attribute__((ext_vector_type(8))) short;

__device__ __host__ __forceinline__ constexpr int tri_(int n) { return n * (n + 1) / 2; }
__device__ __host__ __forceinline__ constexpr int tet_(int n) { return n * (n + 1) * (n + 2) / 6; }

// ---- compile-time multiset table: P(m) = XX[a]*XX[b]*XX[c], XX[16]=1, XX[17]=0
struct MTab { unsigned char a[MTOT], b[MTOT], c[MTOT]; };
constexpr MTab mkMT() {
  MTab t = {};
  int m = 0;
  for (int a = 0; a < 16; a++)
    for (int b = a; b < 16; b++)
      for (int c = b; c < 16; c++) { t.a[m] = a; t.b[m] = b; t.c[m] = c; ++m; }
  for (int a = 0; a < 16; a++)
    for (int b = a; b < 16; b++) { t.a[m] = a; t.b[m] = b; t.c[m] = 16; ++m; }
  for (int a = 0; a < 16; a++) { t.a[m] = a; t.b[m] = 16; t.c[m] = 16; ++m; }
  while (m < MTOT) { t.a[m] = 17; t.b[m] = 17; t.c[m] = 17; ++m; }
  return t;
}
constexpr MTab MT = mkMT();

// ---------------- prep: U rows -> hi/lo bf16 B-frags for 32x32x16 ----------
// (verbatim R11) B-frag: lane l holds Uemb[m = ch*16 + (l>>5)*8 + j][l&31],
// dword p = (m=2p, 2p+1) as (lo,hi) -- same k-placement as the A-side pk.
__global__ void prep_kernel(const float* __restrict__ U3, const float* __restrict__ U2,
                            const float* __restrict__ U1, unsigned short* __restrict__ wsFrag) {
  __shared__ float sRow[16][36];
  const int ch = blockIdx.x;       // 0..60
  const int tid = threadIdx.x;     // 0..127
  if (tid < 16) {
    const int m = ch * 16 + tid;
    for (int i = 0; i < 36; i++) sRow[tid][i] = 0.f;
    if (m < NM3) {
      int ia = 0;
      while (tet_(16) - tet_(16 - (ia + 1)) <= m) ia++;
      int rem = m - (tet_(16) - tet_(16 - ia));
      int ib = ia;
      while (tri_(16 - ia) - tri_(16 - (ib + 1)) <= rem) ib++;
      int ic = ib + (rem - (tri_(16 - ia) - tri_(16 - ib)));
      int pw[6] = {ia, ia, ib, ib, ic, ic};
      int pv[6] = {ib, ic, ia, ic, ia, ib};
      int pi[6] = {ic, ib, ic, ia, ib, ia};
      bool use[6];
      for (int p = 0; p < 6; p++) {
        bool dup = false;
        for (int q = 0; q < p; q++)
          dup = dup || (pw[p] == pw[q] && pv[p] == pv[q] && pi[p] == pi[q]);
        use[p] = !dup;
      }
      for (int k = 0; k < K3_; k++) {
        float s = 0.f;
        for (int p = 0; p < 6; p++)
          if (use[p]) s += U3[((pw[p] * L_ + pv[p]) * L_ + pi[p]) * K3_ + k];
        sRow[tid][k] = s;
      }
    } else if (m < NM3 + NM2) {
      const int pidx = m - NM3;
      int ia = 0;
      while (136 - tri_(16 - (ia + 1)) <= pidx) ia++;
      int ib = ia + (pidx - (136 - tri_(16 - ia)));
      for (int k2 = 0; k2 < K2_; k2++) {
        float s = U2[(ia * L_ + ib) * K2_ + k2];
        if (ia != ib) s += U2[(ib * L_ + ia) * K2_ + k2];
        sRow[tid][23 + k2] = s;
      }
    } else if (m < NM3 + NM2 + L_) {
      sRow[tid][27] = U1[m - NM3 - NM2];
    }
  }
  __syncthreads();
  {
    const int lane = tid & 63, part = tid >> 6;   // part 0 = hi-bf16, 1 = lo-residual
    unsigned short v16[8];
    for (int j = 0; j < 8; j++) {
      float v = sRow[(lane >> 5) * 8 + j][lane & 31];
      unsigned vb = __float_as_uint(v);
      unsigned short h = (unsigned short)(vb >> 16);        // RTZ bf16 hi
      if (part == 0) {
        v16[j] = h;
      } else {
        float lres = v - __uint_as_float(((unsigned)h) << 16);  // exact residual
        v16[j] = (unsigned short)(__float_as_uint(lres) >> 16);
      }
    }
    unsigned* dst = (unsigned*)(wsFrag + ((size_t)(ch * 2 + part) * 64 + lane) * 8);
    for (int p = 0; p < 4; p++)
      dst[p] = (unsigned)v16[2 * p] | ((unsigned)v16[2 * p + 1] << 16);
  }
}

// ---------------- permlane32_swap: vdst.hi <-> vsrc.lo (both updated) ------
__device__ __forceinline__ void lane32_swap(unsigned& a, unsigned& b) {
#if defined(__has_builtin) && __has_builtin(__builtin_amdgcn_permlane32_swap)
  auto r = __builtin_amdgcn_permlane32_swap((int)a, (int)b, false, false);
  a = (unsigned)r[0];
  b = (unsigned)r[1];
#else
  asm volatile("v_permlane32_swap_b32 %0, %1" : "+v"(a), "+v"(b));
#endif
}

// ---------------- main k-loop body, CH as TEMPLATE param -------------------
// 2-deep B prefetch: set (CH&1) holds chunk CH's B; after consuming, the same
// set is re-loaded with chunk CH+2. Named pairs -> static indexing (rule #20).
template <int CH>
__device__ __forceinline__ void chunk_body(
    const float (&XX)[18], const float4* __restrict__ Bg, int lane,
    float4& nbH0, float4& nbL0, float4& nbH1, float4& nbL1,
    f32x16& acc0, f32x16& acc1) {
  // P for THIS lane's channel: k-slice 0 -> pk0, k-slice 1 -> pk1.
  unsigned pk0[4], pk1[4];
  #pragma unroll
  for (int i = 0; i < 4; ++i) {
    {
      const int m0 = CH * 16 + 2 * i;
      float p0 = XX[MT.a[m0]] * XX[MT.b[m0]] * XX[MT.c[m0]];
      float p1 = XX[MT.a[m0 + 1]] * XX[MT.b[m0 + 1]] * XX[MT.c[m0 + 1]];
      asm("v_cvt_pk_bf16_f32 %0, %1, %2" : "=v"(pk0[i]) : "v"(p0), "v"(p1));
    }
    {
      const int m0 = CH * 16 + 8 + 2 * i;
      float p0 = XX[MT.a[m0]] * XX[MT.b[m0]] * XX[MT.c[m0]];
      float p1 = XX[MT.a[m0 + 1]] * XX[MT.b[m0 + 1]] * XX[MT.c[m0 + 1]];
      asm("v_cvt_pk_bf16_f32 %0, %1, %2" : "=v"(pk1[i]) : "v"(p0), "v"(p1));
    }
    // A0 = {lo: own pk0, hi: partner pk1}; A1 = {lo: partner pk0, hi: own pk1}
    lane32_swap(pk0[i], pk1[i]);
  }

  // consume this chunk's prefetched B set; reissue the set for CH+2
  float4 bh, bl;
  if constexpr ((CH & 1) == 0) { bh = nbH0; bl = nbL0; } else { bh = nbH1; bl = nbL1; }
  if constexpr (CH + 2 < NCH2) {
    if constexpr ((CH & 1) == 0) {
      nbH0 = Bg[(CH + 2) * 128 + lane];
      nbL0 = Bg[(CH + 2) * 128 + 64 + lane];
    } else {
      nbH1 = Bg[(CH + 2) * 128 + lane];
      nbL1 = Bg[(CH + 2) * 128 + 64 + lane];
    }
  }
  short8v A0, A1, BH, BL;
  __builtin_memcpy(&A0, pk0, 16);
  __builtin_memcpy(&A1, pk1, 16);
  __builtin_memcpy(&BH, &bh, 16);
  __builtin_memcpy(&BL, &bl, 16);

  acc0 = __builtin_amdgcn_mfma_f32_32x32x16_bf16(A0, BH, acc0, 0, 0, 0);
  acc1 = __builtin_amdgcn_mfma_f32_32x32x16_bf16(A1, BH, acc1, 0, 0, 0);
  acc0 = __builtin_amdgcn_mfma_f32_32x32x16_bf16(A0, BL, acc0, 0, 0, 0);
  acc1 = __builtin_amdgcn_mfma_f32_32x32x16_bf16(A1, BL, acc1, 0, 0, 0);
}

template <int CH>
struct Loop {
  static __device__ __forceinline__ void run(
      const float (&XX)[18], const float4* __restrict__ Bg, int lane,
      float4& nbH0, float4& nbL0, float4& nbH1, float4& nbL1,
      f32x16& acc0, f32x16& acc1) {
    chunk_body<CH>(XX, Bg, lane, nbH0, nbL0, nbH1, nbL1, acc0, acc1);
    Loop<CH + 1>::run(XX, Bg, lane, nbH0, nbL0, nbH1, nbL1, acc0, acc1);
  }
};
template <>
struct Loop<NCH2> {
  static __device__ __forceinline__ void run(
      const float (&)[18], const float4* __restrict__, int,
      float4&, float4&, float4&, float4&, f32x16&, f32x16&) {}
};

// ONE WAVE per block: 64 threads. grid = 4096: block bb -> b = bb>>2,
// channel group cg = bb&3; lane l owns channel c = cg*64 + l.
// acc0 = channels cg*64+0..31, acc1 = +32. ZERO barriers (D-transpose via
// own-wave sT band: ds_write -> ds_read same wave, in-order).
// (64,2): allocator's observed pattern targets 2x min = 4 waves/EU = 128 regs.
__global__ __launch_bounds__(64, 2) void symcon_kernel(
    const float* __restrict__ x,   // [B,C,L]
    const float* __restrict__ y,   // [B,E]
    const float* __restrict__ W3,  // [E,K3,C]
    const float* __restrict__ W2,  // [E,K2,C]
    const float* __restrict__ W1,  // [E,1,C]
    const unsigned short* __restrict__ wsFrag,
    float* __restrict__ out)       // [B,C]
{
  __shared__ __attribute__((aligned(16))) float sT[28 * STSTR];  // 7616 B

  const int lane = threadIdx.x;            // 0..63
  const int bb = blockIdx.x;
  const int b = bb >> 2;
  const int c = (bb & 3) * 64 + lane;      // this lane's channel

  // x row of this thread's channel -> 18 registers (constant indices only)
  float XX[18];
  {
    const float4* xg = (const float4*)(x + ((size_t)b * C_ + c) * L_);
    #pragma unroll
    for (int i = 0; i < 4; i++) {
      float4 v = xg[i];
      XX[i * 4 + 0] = v.x; XX[i * 4 + 1] = v.y;
      XX[i * 4 + 2] = v.z; XX[i * 4 + 3] = v.w;
    }
    XX[16] = 1.f; XX[17] = 0.f;
  }

  const float4* Bg = (const float4*)wsFrag;
  float4 nbH0 = Bg[lane],        nbL0 = Bg[64 + lane];        // chunk 0
  float4 nbH1 = Bg[128 + lane],  nbL1 = Bg[192 + lane];       // chunk 1
  f32x16 acc0 = (f32x16)0.f, acc1 = (f32x16)0.f;

  Loop<0>::run(XX, Bg, lane, nbH0, nbL0, nbH1, nbL1, acc0, acc1);

  // ---- D -> sT transpose (own wave only; no barrier). D layout
  // (m74/m101-verified): lane l, reg r holds
  // t[ch = (r&3)+8*(r>>2)+4*(l>>5) (+32 for acc1)][kcol = l&31].
  const int kcol = lane & 31, hi = lane >> 5;
  if (kcol < 28) {
    #pragma unroll
    for (int q = 0; q < 4; ++q) {
      f32x4 v0, v1;
      #pragma unroll
      for (int i2 = 0; i2 < 4; ++i2) {
        v0[i2] = acc0[4 * q + i2];
        v1[i2] = acc1[4 * q + i2];
      }
      *(f32x4*)&sT[kcol * STSTR +      8 * q + 4 * hi] = v0;
      *(f32x4*)&sT[kcol * STSTR + 32 + 8 * q + 4 * hi] = v1;
    }
  }
  // same-wave DS in-order; compiler sees aliasing (no __restrict__ on sT)
  float t[28];
  #pragma unroll
  for (int k = 0; k < 28; ++k) t[k] = sT[k * STSTR + lane];

  // ---- epilogue (verbatim math from verified rounds) ----
  float yreg[E_];
  #pragma unroll
  for (int e = 0; e < E_; e++) yreg[e] = y[b * E_ + e];

  float result = 0.f;
  #pragma unroll
  for (int k = 0; k < K3_; k++) {
    const float* w3p = &W3[k * C_ + c];
    float w3k = 0.f;
    #pragma unroll
    for (int e = 0; e < E_; e++) w3k += w3p[e * K3_ * C_] * yreg[e];
    result += t[k] * w3k;
  }
  #pragma unroll
  for (int k2 = 0; k2 < K2_; k2++) {
    const float* w2p = &W2[k2 * C_ + c];
    float w2k = 0.f;
    #pragma unroll
    for (int e = 0; e < E_; e++) w2k += w2p[e * K2_ * C_] * yreg[e];
    result += t[23 + k2] * w2k;
  }
  {
    float w1v = 0.f;
    #pragma unroll
    for (int e = 0; e < E_; e++) w1v += W1[e * C_ + c] * yreg[e];
    result += t[27] * w1v;
  }

  out[(size_t)b * C_ + c] = result;
}

extern "C" void kernel_launch(void* const* d_in, const int* in_sizes, int n_in,
                              void* d_out, int out_size, void* d_ws, size_t ws_size,
                              hipStream_t stream) {
  const float* x  = (const float*)d_in[0];
  const float* y  = (const float*)d_in[1];
  const float* U3 = (const float*)d_in[2];
  const float* U2 = (const float*)d_in[3];
  const float* U1 = (const float*)d_in[4];
  const float* W3 = (const float*)d_in[5];
  const float* W2 = (const float*)d_in[6];
  const float* W1 = (const float*)d_in[7];
  float* out = (float*)d_out;

  unsigned short* wsFrag = (unsigned short*)d_ws;  // 61*2*64*8 u16 = 124928 B

  prep_kernel<<<dim3(NCH2), dim3(128), 0, stream>>>(U3, U2, U1, wsFrag);
  symcon_kernel<<<dim3(B_ * 4), dim3(64), 0, stream>>>(
      x, y, W3, W2, W1, wsFrag, out);
}

// Round 14
// 119.155 us; speedup vs baseline: 1.2680x; 1.0888x over previous
//
#include <hip/hip_runtime.h>

// SymmetricContraction as ONE bf16 MFMA GEMM (32x32x16):
//   t[ch, k] = sum_m P[ch, m] * Uemb[m, k], 976 embedded rows, 61 K=16 chunks:
//     m   0..815 : triples a<=b<=c   P = xa*xb*xc, cols 0..22  = U3sym
//     m 816..951 : pairs  a<=b       P = xa*xb,    cols 23..26 = U2sym
//     m 952..967 : singles w         P = xw,       col  27     = U1
//     m 968..975 : zero pad
//
// Round-13 (recompiled): SINGLE-bf16 U (lo-residual MFMA dropped). R11/R12
// were invariant at ~50us across block-geometry changes -> binding resources
// are the per-wave B-stream (122KB L2), MFMA issue, acc register weight.
// Single-U halves all three. Precision: threshold 16.64 (bf16 floor-eps);
// hi/lo build measured absmax 2.0 (P-rounding dominated); + same-order
// U-rounding -> predicted ~3-5.
// R13 compile fix: pval<M> was instantiated with a RUNTIME loop index
// (#pragma unroll does not make `i` a constant-expression). Now pk_pair<CH,I>
// is explicitly instantiated at I=0..3 -> all M are true constants.

#define B_   1024
#define C_   256
#define L_   16
#define E_   10
#define K3_  23
#define K2_  4

#define NM3  816
#define NM2  136
#define MTOT 992
#define NCH2 61      // K=16 chunks 0..60
#define STSTR 68     // sT row stride in floats (28 x 68 x 4 = 7616 B)

using f32x4   = __attribute__((ext_vector_type(4))) float;
using f32x16  = __attribute__((ext_vector_type(16))) float;
using short8v = __attribute__((ext_vector_type(8))) short;

__device__ __host__ __forceinline__ constexpr int tri_(int n) { return n * (n + 1) / 2; }
__device__ __host__ __forceinline__ constexpr int tet_(int n) { return n * (n + 1) * (n + 2) / 6; }

// ---- compile-time multiset table: a<=b<=c triples, then pairs (c=16),
// singles (b=c=16), pad (a=17).
struct MTab { unsigned char a[MTOT], b[MTOT], c[MTOT]; };
constexpr MTab mkMT() {
  MTab t = {};
  int m = 0;
  for (int a = 0; a < 16; a++)
    for (int b = a; b < 16; b++)
      for (int c = b; c < 16; c++) { t.a[m] = a; t.b[m] = b; t.c[m] = c; ++m; }
  for (int a = 0; a < 16; a++)
    for (int b = a; b < 16; b++) { t.a[m] = a; t.b[m] = b; t.c[m] = 16; ++m; }
  for (int a = 0; a < 16; a++) { t.a[m] = a; t.b[m] = 16; t.c[m] = 16; ++m; }
  while (m < MTOT) { t.a[m] = 17; t.b[m] = 17; t.c[m] = 17; ++m; }
  return t;
}
constexpr MTab MT = mkMT();

// ---------------- prep: U rows -> single-bf16 B-frags for 32x32x16 --------
// grid = 61 blocks x 64 threads. Threads 0..15 build the 16 U-rows of chunk
// ch in LDS (closed-form m -> indices); all 64 pack the bf16 frag.
// B-frag: lane l holds Uemb[m = ch*16 + (l>>5)*8 + j][col = l&31], j asc,
// dword p = (m=2p, 2p+1) as (lo,hi) -- same k-placement as the A-side pk
// (convention verified by R11/R12 passing).
__global__ void prep_kernel(const float* __restrict__ U3, const float* __restrict__ U2,
                            const float* __restrict__ U1, unsigned short* __restrict__ wsFrag) {
  __shared__ float sRow[16][36];
  const int ch = blockIdx.x;       // 0..60
  const int tid = threadIdx.x;     // 0..63
  if (tid < 16) {
    const int m = ch * 16 + tid;
    for (int i = 0; i < 36; i++) sRow[tid][i] = 0.f;
    if (m < NM3) {
      int ia = 0;
      while (tet_(16) - tet_(16 - (ia + 1)) <= m) ia++;
      int rem = m - (tet_(16) - tet_(16 - ia));
      int ib = ia;
      while (tri_(16 - ia) - tri_(16 - (ib + 1)) <= rem) ib++;
      int ic = ib + (rem - (tri_(16 - ia) - tri_(16 - ib)));
      int pw[6] = {ia, ia, ib, ib, ic, ic};
      int pv[6] = {ib, ic, ia, ic, ia, ib};
      int pi[6] = {ic, ib, ic, ia, ib, ia};
      bool use[6];
      for (int p = 0; p < 6; p++) {
        bool dup = false;
        for (int q = 0; q < p; q++)
          dup = dup || (pw[p] == pw[q] && pv[p] == pv[q] && pi[p] == pi[q]);
        use[p] = !dup;
      }
      for (int k = 0; k < K3_; k++) {
        float s = 0.f;
        for (int p = 0; p < 6; p++)
          if (use[p]) s += U3[((pw[p] * L_ + pv[p]) * L_ + pi[p]) * K3_ + k];
        sRow[tid][k] = s;
      }
    } else if (m < NM3 + NM2) {
      const int pidx = m - NM3;
      int ia = 0;
      while (136 - tri_(16 - (ia + 1)) <= pidx) ia++;
      int ib = ia + (pidx - (136 - tri_(16 - ia)));
      for (int k2 = 0; k2 < K2_; k2++) {
        float s = U2[(ia * L_ + ib) * K2_ + k2];
        if (ia != ib) s += U2[(ib * L_ + ia) * K2_ + k2];
        sRow[tid][23 + k2] = s;
      }
    } else if (m < NM3 + NM2 + L_) {
      sRow[tid][27] = U1[m - NM3 - NM2];
    }
  }
  __syncthreads();
  {
    const int lane = tid;
    unsigned short v16[8];
    for (int j = 0; j < 8; j++) {
      float v = sRow[(lane >> 5) * 8 + j][lane & 31];
      // bf16 round-half-up (same error class as RNE; |err| <= 0.5 ulp16)
      unsigned vb = __float_as_uint(v) + 0x8000u;
      v16[j] = (unsigned short)(vb >> 16);
    }
    unsigned* dst = (unsigned*)(wsFrag + ((size_t)ch * 64 + lane) * 8);
    for (int p = 0; p < 4; p++)
      dst[p] = (unsigned)v16[2 * p] | ((unsigned)v16[2 * p + 1] << 16);
  }
}

// ---------------- permlane32_swap: vdst.hi <-> vsrc.lo (both updated) ------
__device__ __forceinline__ void lane32_swap(unsigned& a, unsigned& b) {
#if defined(__has_builtin) && __has_builtin(__builtin_amdgcn_permlane32_swap)
  auto r = __builtin_amdgcn_permlane32_swap((int)a, (int)b, false, false);
  a = (unsigned)r[0];
  b = (unsigned)r[1];
#else
  asm volatile("v_permlane32_swap_b32 %0, %1" : "+v"(a), "+v"(b));
#endif
}

// P(m) with compile-time specialization (constexpr MT): triples 2 muls,
// pairs 1 mul, singles 0 muls, pad exact 0. M is a true template constant.
template <int M>
__device__ __forceinline__ float pval(const float (&XX)[16]) {
  if constexpr (MT.a[M] == 17) return 0.f;
  else if constexpr (MT.b[M] == 16) return XX[MT.a[M]];
  else if constexpr (MT.c[M] == 16) return XX[MT.a[M]] * XX[MT.b[M]];
  else return XX[MT.a[M]] * XX[MT.b[M]] * XX[MT.c[M]];
}

// one pk dword for each k-slice at position I (I is a template constant —
// the R13 compile failure was using a runtime loop index here)
template <int CH, int I>
__device__ __forceinline__ void pk_pair(const float (&XX)[16],
                                        unsigned& o0, unsigned& o1) {
  {
    float p0 = pval<CH * 16 + 2 * I>(XX);
    float p1 = pval<CH * 16 + 2 * I + 1>(XX);
    asm("v_cvt_pk_bf16_f32 %0, %1, %2" : "=v"(o0) : "v"(p0), "v"(p1));
  }
  {
    float p0 = pval<CH * 16 + 8 + 2 * I>(XX);
    float p1 = pval<CH * 16 + 8 + 2 * I + 1>(XX);
    asm("v_cvt_pk_bf16_f32 %0, %1, %2" : "=v"(o1) : "v"(p0), "v"(p1));
  }
  // A0 = {lo: own slice0, hi: partner slice1}; A1 = {lo: partner s0, hi: own s1}
  lane32_swap(o0, o1);
}

// ---------------- main k-loop body, CH as TEMPLATE param -------------------
// 2-deep B prefetch, named sets by parity (static indexing, rule #20).
template <int CH>
__device__ __forceinline__ void chunk_body(
    const float (&XX)[16], const float4* __restrict__ Bg, int lane,
    float4& nb0, float4& nb1, f32x16& acc0, f32x16& acc1) {
  unsigned pk0[4], pk1[4];
  pk_pair<CH, 0>(XX, pk0[0], pk1[0]);
  pk_pair<CH, 1>(XX, pk0[1], pk1[1]);
  pk_pair<CH, 2>(XX, pk0[2], pk1[2]);
  pk_pair<CH, 3>(XX, pk0[3], pk1[3]);

  // consume this chunk's prefetched B; reissue the set for CH+2 (L2-resident)
  float4 bh;
  if constexpr ((CH & 1) == 0) bh = nb0; else bh = nb1;
  if constexpr (CH + 2 < NCH2) {
    if constexpr ((CH & 1) == 0) nb0 = Bg[(CH + 2) * 64 + lane];
    else                         nb1 = Bg[(CH + 2) * 64 + lane];
  }
  short8v A0, A1, BH;
  __builtin_memcpy(&A0, pk0, 16);
  __builtin_memcpy(&A1, pk1, 16);
  __builtin_memcpy(&BH, &bh, 16);

  acc0 = __builtin_amdgcn_mfma_f32_32x32x16_bf16(A0, BH, acc0, 0, 0, 0);
  acc1 = __builtin_amdgcn_mfma_f32_32x32x16_bf16(A1, BH, acc1, 0, 0, 0);
}

template <int CH>
struct Loop {
  static __device__ __forceinline__ void run(
      const float (&XX)[16], const float4* __restrict__ Bg, int lane,
      float4& nb0, float4& nb1, f32x16& acc0, f32x16& acc1) {
    chunk_body<CH>(XX, Bg, lane, nb0, nb1, acc0, acc1);
    Loop<CH + 1>::run(XX, Bg, lane, nb0, nb1, acc0, acc1);
  }
};
template <>
struct Loop<NCH2> {
  static __device__ __forceinline__ void run(
      const float (&)[16], const float4* __restrict__, int,
      float4&, float4&, f32x16&, f32x16&) {}
};

// ONE WAVE per block: 64 threads. grid = 4096: block bb -> b = bb>>2,
// channel group cg = bb&3; lane l owns channel c = cg*64 + l.
// acc0 = channels cg*64+0..31, acc1 = +32. ZERO barriers.
__global__ __launch_bounds__(64, 2) void symcon_kernel(
    const float* __restrict__ x,   // [B,C,L]
    const float* __restrict__ y,   // [B,E]
    const float* __restrict__ W3,  // [E,K3,C]
    const float* __restrict__ W2,  // [E,K2,C]
    const float* __restrict__ W1,  // [E,1,C]
    const unsigned short* __restrict__ wsFrag,
    float* __restrict__ out)       // [B,C]
{
  __shared__ __attribute__((aligned(16))) float sT[28 * STSTR];  // 7616 B

  const int lane = threadIdx.x;            // 0..63
  const int bb = blockIdx.x;
  const int b = bb >> 2;
  const int c = (bb & 3) * 64 + lane;      // this lane's channel

  // x row of this thread's channel -> 16 registers (constant indices only)
  float XX[16];
  {
    const float4* xg = (const float4*)(x + ((size_t)b * C_ + c) * L_);
    #pragma unroll
    for (int i = 0; i < 4; i++) {
      float4 v = xg[i];
      XX[i * 4 + 0] = v.x; XX[i * 4 + 1] = v.y;
      XX[i * 4 + 2] = v.z; XX[i * 4 + 3] = v.w;
    }
  }

  const float4* Bg = (const float4*)wsFrag;
  float4 nb0 = Bg[lane], nb1 = Bg[64 + lane];   // chunks 0, 1
  f32x16 acc0 = (f32x16)0.f, acc1 = (f32x16)0.f;

  Loop<0>::run(XX, Bg, lane, nb0, nb1, acc0, acc1);

  // ---- D -> sT transpose (own wave only; no barrier). D layout
  // (m74/m101-verified): lane l, reg r holds
  // t[ch = (r&3)+8*(r>>2)+4*(l>>5) (+32 for acc1)][kcol = l&31].
  const int kcol = lane & 31, hi = lane >> 5;
  if (kcol < 28) {
    #pragma unroll
    for (int q = 0; q < 4; ++q) {
      f32x4 v0, v1;
      #pragma unroll
      for (int i2 = 0; i2 < 4; ++i2) {
        v0[i2] = acc0[4 * q + i2];
        v1[i2] = acc1[4 * q + i2];
      }
      *(f32x4*)&sT[kcol * STSTR +      8 * q + 4 * hi] = v0;
      *(f32x4*)&sT[kcol * STSTR + 32 + 8 * q + 4 * hi] = v1;
    }
  }
  // same-wave DS in-order; compiler sees aliasing (no __restrict__ on sT)
  float t[28];
  #pragma unroll
  for (int k = 0; k < 28; ++k) t[k] = sT[k * STSTR + lane];

  // ---- epilogue (verbatim math from verified rounds) ----
  float yreg[E_];
  #pragma unroll
  for (int e = 0; e < E_; e++) yreg[e] = y[b * E_ + e];

  float result = 0.f;
  #pragma unroll
  for (int k = 0; k < K3_; k++) {
    const float* w3p = &W3[k * C_ + c];
    float w3k = 0.f;
    #pragma unroll
    for (int e = 0; e < E_; e++) w3k += w3p[e * K3_ * C_] * yreg[e];
    result += t[k] * w3k;
  }
  #pragma unroll
  for (int k2 = 0; k2 < K2_; k2++) {
    const float* w2p = &W2[k2 * C_ + c];
    float w2k = 0.f;
    #pragma unroll
    for (int e = 0; e < E_; e++) w2k += w2p[e * K2_ * C_] * yreg[e];
    result += t[23 + k2] * w2k;
  }
  {
    float w1v = 0.f;
    #pragma unroll
    for (int e = 0; e < E_; e++) w1v += W1[e * C_ + c] * yreg[e];
    result += t[27] * w1v;
  }

  out[(size_t)b * C_ + c] = result;
}

extern "C" void kernel_launch(void* const* d_in, const int* in_sizes, int n_in,
                              void* d_out, int out_size, void* d_ws, size_t ws_size,
                              hipStream_t stream) {
  const float* x  = (const float*)d_in[0];
  const float* y  = (const float*)d_in[1];
  const float* U3 = (const float*)d_in[2];
  const float* U2 = (const float*)d_in[3];
  const float* U1 = (const float*)d_in[4];
  const float* W3 = (const float*)d_in[5];
  const float* W2 = (const float*)d_in[6];
  const float* W1 = (const float*)d_in[7];
  float* out = (float*)d_out;

  unsigned short* wsFrag = (unsigned short*)d_ws;  // 61*64*8 u16 = 62464 B

  prep_kernel<<<dim3(NCH2), dim3(64), 0, stream>>>(U3, U2, U1, wsFrag);
  symcon_kernel<<<dim3(B_ * 4), dim3(64), 0, stream>>>(
      x, y, W3, W2, W1, wsFrag, out);
}